// Round 10
// baseline (2195.562 us; speedup 1.0000x reference)
//
#include <hip/hip_runtime.h>
#include <hip/hip_bf16.h>

// ---------------- problem constants ----------------
#define DIMC   512
#define HEADS  8
#define DH     64
#define MLM    256          // landmarks
#define NPATCH 40000
#define NTOK   40001        // with cls
#define PADF   191          // front zero pad
#define NSEQ   40192        // NTOK + PADF
#define NSEQP  40224        // NSEQ + 32 (zero pad for flash tiles)
#define LWIN   157          // NSEQ / MLM
#define INDIM  1024
#define GRID   200
#define CHUNKS 64
#define PER    628          // NSEQ / CHUNKS

typedef _Float16 h8 __attribute__((ext_vector_type(8)));
typedef _Float16 h4 __attribute__((ext_vector_type(4)));
typedef float    f4 __attribute__((ext_vector_type(4)));
typedef float    f2 __attribute__((ext_vector_type(2)));

// wave-local ordering fence: DS ops from one wave complete in order; this
// stops the COMPILER from reordering LDS ops across the point and drains
// outstanding LDS returns. Much cheaper than __syncthreads for per-wave LDS.
#define WAVE_LDS_FENCE() asm volatile("s_waitcnt lgkmcnt(0)" ::: "memory")

// async global->LDS, 16B per lane; LDS dest = wave-uniform base + lane*16
__device__ __forceinline__ void gl_lds(const _Float16* g, _Float16* l) {
  __builtin_amdgcn_global_load_lds(
      (const __attribute__((address_space(1))) void*)g,
      (__attribute__((address_space(3))) void*)l, 16, 0, 0);
}

// ---------------- reductions ----------------
template<int NW, bool ISMAX>
__device__ __forceinline__ float blkRed(float v, float* s) {
  #pragma unroll
  for (int o = 32; o; o >>= 1) {
    float t = __shfl_down(v, o, 64);
    v = ISMAX ? fmaxf(v, t) : v + t;
  }
  int lane = threadIdx.x & 63, w = threadIdx.x >> 6;
  __syncthreads();
  if (lane == 0) s[w] = v;
  __syncthreads();
  float r = s[0];
  #pragma unroll
  for (int i = 1; i < NW; i++) r = ISMAX ? fmaxf(r, s[i]) : r + s[i];
  return r;
}

// ---------------- misc small kernels ----------------
__global__ __launch_bounds__(512)
void k_set_cls(const float* __restrict__ cls, float* __restrict__ h) {
  h[threadIdx.x] = cls[threadIdx.x];
}

__global__ __launch_bounds__(256)
void k_f32_to_f16(const float* __restrict__ in, _Float16* __restrict__ out) {
  int i = blockIdx.x * 256 + threadIdx.x;
  float4 v = ((const float4*)in)[i];
  h4 o = {(_Float16)v.x, (_Float16)v.y, (_Float16)v.z, (_Float16)v.w};
  *(h4*)(out + (size_t)i * 4) = o;
}

// zero the 32-row pads of q16/k16/v16 (8 heads x 32 rows x 64)
__global__ __launch_bounds__(256)
void k_zpad(_Float16* q16, _Float16* k16, _Float16* v16) {
  int idx = blockIdx.x * 256 + threadIdx.x;       // 16384 total
  int h = idx >> 11, r = (idx >> 6) & 31, d = idx & 63;
  size_t a = ((size_t)h * NSEQP + NSEQ + r) * 64 + d;
  q16[a] = (_Float16)0.f; k16[a] = (_Float16)0.f; v16[a] = (_Float16)0.f;
}

// weight K x N fp32 -> transposed N x K fp16
__global__ __launch_bounds__(256)
void k_wt16(const float* __restrict__ B, _Float16* __restrict__ Bt, int K, int N)
{
  __shared__ float tile[32][33];
  int kb = blockIdx.x * 32, nb = blockIdx.y * 32;
  int x = threadIdx.x & 31, y0 = threadIdx.x >> 5;
  #pragma unroll
  for (int yy = y0; yy < 32; yy += 8)
    tile[yy][x] = B[(size_t)(kb + yy) * N + nb + x];
  __syncthreads();
  #pragma unroll
  for (int yy = y0; yy < 32; yy += 8)
    Bt[(size_t)(nb + yy) * K + kb + x] = (_Float16)tile[x][yy];
}

// ---------------- fp16 MFMA GEMM: 128x128 tile, swapped-operand epilogue ----------------
// XCD-aware A-reuse schedule (T1, bijective): 1-D grid; the NT column-panels of
// one M-tile run consecutively ON THE SAME XCD (bid%8 = xcd round-robin), so the
// A-tile is an L2 hit for NT-1 of NT reads instead of L3/HBM re-fetches.
// mfma(bf, af): acc reg axis -> 4 consecutive N-cols, lane&15 -> M-rows
// => coalesced h4 (qkv scatter) / float4 (fp32 C) stores.
// flags: 1 = relu, 2 = accumulate into C, 4 = qkv scatter store (fp16 head-major)
__global__ __launch_bounds__(256)
void k_gemm16(const _Float16* __restrict__ A, const _Float16* __restrict__ Bt,
              const float* __restrict__ bias, float* __restrict__ C,
              _Float16* __restrict__ q16, _Float16* __restrict__ k16, _Float16* __restrict__ v16,
              int Mr, int K, int N, int flags)
{
  __shared__ __attribute__((aligned(16))) _Float16 As[128 * 32];
  __shared__ __attribute__((aligned(16))) _Float16 Bs[128 * 32];
  int NT = N >> 7;
  int nwg = gridDim.x;
  int q8 = nwg >> 3, r8 = nwg & 7;
  int xcd = blockIdx.x & 7, sidx = blockIdx.x >> 3;
  int wgid = (xcd < r8) ? (xcd * (q8 + 1) + sidx)
                        : (r8 * (q8 + 1) + (xcd - r8) * q8 + sidx);
  int bm = (wgid / NT) * 128, bn = (wgid % NT) * 128;
  int t = threadIdx.x;
  int lane = t & 63, w = t >> 6;
  int wm = (w >> 1) * 64, wn = (w & 1) * 64;
  int r = lane & 15, q = lane >> 4;
  int sub = lane >> 2;            // row within 16-row staging group
  int kq = (lane & 3) * 8;        // col (halves) within row

  const f4 zero = {0.f, 0.f, 0.f, 0.f};
  f4 acc[4][4];
  #pragma unroll
  for (int mi = 0; mi < 4; mi++)
    #pragma unroll
    for (int nj = 0; nj < 4; nj++) acc[mi][nj] = zero;

  for (int k0 = 0; k0 < K; k0 += 32) {
    #pragma unroll
    for (int c = 0; c < 2; c++) {
      int rowA = (w * 2 + c) * 16 + sub;
      int gmA = bm + rowA; if (gmA > Mr - 1) gmA = Mr - 1;
      gl_lds(A  + (size_t)gmA * K + k0 + kq,          As + (w * 2 + c) * 512);
      gl_lds(Bt + (size_t)(bn + rowA) * K + k0 + kq,  Bs + (w * 2 + c) * 512);
    }
    __syncthreads();
    h8 af[4], bf[4];
    #pragma unroll
    for (int i = 0; i < 4; i++) {
      af[i] = *(const h8*)(As + (wm + i * 16 + r) * 32 + q * 8);
      bf[i] = *(const h8*)(Bs + (wn + i * 16 + r) * 32 + q * 8);
    }
    #pragma unroll
    for (int mi = 0; mi < 4; mi++)
      #pragma unroll
      for (int nj = 0; nj < 4; nj++)
        acc[mi][nj] = __builtin_amdgcn_mfma_f32_16x16x32_f16(bf[nj], af[mi], acc[mi][nj], 0, 0, 0);
    __syncthreads();
  }
  #pragma unroll
  for (int mi = 0; mi < 4; mi++) {
    int gm = bm + wm + mi * 16 + r;
    if (gm >= Mr) continue;
    #pragma unroll
    for (int nj = 0; nj < 4; nj++) {
      int gn = bn + wn + nj * 16 + q * 4;
      f4 v = acc[mi][nj];
      if (flags & 4) {
        int which = gn >> 9, hh = (gn >> 6) & 7, dd = gn & 63;
        _Float16* dst = (which == 0) ? q16 : (which == 1) ? k16 : v16;
        h4 o = {(_Float16)v[0], (_Float16)v[1], (_Float16)v[2], (_Float16)v[3]};
        *(h4*)(dst + ((size_t)hh * NSEQP + gm) * 64 + dd) = o;
      } else {
        if (bias) { f4 bv = *(const f4*)(bias + gn); v += bv; }
        float* cp = C + (size_t)gm * N + gn;
        if (flags & 2) { f4 cv = *(const f4*)cp; v += cv; }
        if (flags & 1) {
          v[0] = fmaxf(v[0], 0.f); v[1] = fmaxf(v[1], 0.f);
          v[2] = fmaxf(v[2], 0.f); v[3] = fmaxf(v[3], 0.f);
        }
        *(f4*)cp = v;
      }
    }
  }
}

// ---------------- layernorm + front zero pad (fp16 out) ----------------
__global__ __launch_bounds__(256)
void k_ln_pad(const float* __restrict__ h, const float* __restrict__ w,
              const float* __restrict__ b, _Float16* __restrict__ xln)
{
  __shared__ float sbuf[8];
  int t = blockIdx.x;
  int tid = threadIdx.x;
  _Float16* out = xln + (size_t)t * DIMC;
  if (t < PADF) { out[tid] = (_Float16)0.f; out[tid + 256] = (_Float16)0.f; return; }
  const float* row = h + (size_t)(t - PADF) * DIMC;
  float x0 = row[tid], x1 = row[tid + 256];
  float mu = blkRed<4,false>(x0 + x1, sbuf) * (1.f / 512.f);
  float d0 = x0 - mu, d1 = x1 - mu;
  float var = blkRed<4,false>(d0 * d0 + d1 * d1, sbuf) * (1.f / 512.f);
  float rstd = rsqrtf(var + 1e-5f);
  out[tid]       = (_Float16)(d0 * rstd * w[tid]       + b[tid]);
  out[tid + 256] = (_Float16)(d1 * rstd * w[tid + 256] + b[tid + 256]);
}

// ---------------- v16 [h][t][64] -> vt16 [h][64][NSEQP] transpose ----------------
__global__ __launch_bounds__(256)
void k_vt(const _Float16* __restrict__ v16, _Float16* __restrict__ vt16)
{
  __shared__ _Float16 tl[64][72];
  int h = blockIdx.y;
  int t0 = blockIdx.x * 64;
  for (int c = threadIdx.x; c < 512; c += 256) {
    int row = c >> 3, ch = (c & 7) * 8;
    h8 v = {};
    if (t0 + row < NSEQP)
      v = *(const h8*)(v16 + ((size_t)h * NSEQP + t0 + row) * 64 + ch);
    *(h8*)&tl[row][ch] = v;
  }
  __syncthreads();
  int d = threadIdx.x & 63, tg = (threadIdx.x >> 6) * 16;
  if (t0 + tg < NSEQP) {
    _Float16 tmp[16];
    #pragma unroll
    for (int k = 0; k < 16; k++) tmp[k] = tl[tg + k][d];
    *(h8*)(vt16 + ((size_t)h * 64 + d) * NSEQP + t0 + tg)     = *(h8*)tmp;
    *(h8*)(vt16 + ((size_t)h * 64 + d) * NSEQP + t0 + tg + 8) = *(h8*)(tmp + 8);
  }
}

// ---------------- landmarks from fp16 q/k ----------------
__global__ __launch_bounds__(256)
void k_landmarks(const _Float16* __restrict__ q16, const _Float16* __restrict__ k16,
                 float* __restrict__ ql, float* __restrict__ kl,
                 _Float16* __restrict__ ql16, _Float16* __restrict__ kl16)
{
  __shared__ float red[2][16][64];
  int h = blockIdx.x >> 8, i = blockIdx.x & 255;
  int jg = threadIdx.x >> 4, d4 = (threadIdx.x & 15) * 4;
  const _Float16* qb = q16 + ((size_t)h * NSEQP + i * LWIN) * 64;
  const _Float16* kb = k16 + ((size_t)h * NSEQP + i * LWIN) * 64;
  float sq[4] = {}, sk[4] = {};
  for (int j = jg; j < LWIN; j += 16) {
    h4 qv = *(const h4*)(qb + j * 64 + d4);
    h4 kv = *(const h4*)(kb + j * 64 + d4);
    #pragma unroll
    for (int c = 0; c < 4; c++) { sq[c] += (float)qv[c]; sk[c] += (float)kv[c]; }
  }
  #pragma unroll
  for (int c = 0; c < 4; c++) { red[0][jg][d4 + c] = sq[c]; red[1][jg][d4 + c] = sk[c]; }
  __syncthreads();
  if (threadIdx.x < 64) {
    int d = threadIdx.x;
    float aq = 0.f, ak = 0.f;
    #pragma unroll
    for (int g = 0; g < 16; g++) { aq += red[0][g][d]; ak += red[1][g][d]; }
    aq *= (0.125f / (float)LWIN);
    ak *= (1.f / (float)LWIN);
    size_t o = ((size_t)h * MLM + i) * DH + d;
    ql[o] = aq; kl[o] = ak;
    ql16[o] = (_Float16)aq;
    kl16[o] = (_Float16)(ak * 0.125f);   // fold q-scale for attn1
  }
}

// ---------------- attn2 = softmax(q_l @ k_l^T) ----------------
__global__ __launch_bounds__(256)
void k_attn2(const float* __restrict__ ql, const float* __restrict__ kl, float* __restrict__ a2)
{
  __shared__ float qrow[DH];
  __shared__ float sbuf[8];
  int h = blockIdx.x >> 8, i = blockIdx.x & 255;
  int j = threadIdx.x;
  if (j < DH) qrow[j] = ql[(h * MLM + i) * DH + j];
  __syncthreads();
  const float* krow = kl + (size_t)(h * MLM + j) * DH;
  float s = 0.f;
  #pragma unroll 16
  for (int d = 0; d < DH; d++) s += qrow[d] * krow[d];
  float mx = blkRed<4,true>(s, sbuf);
  float e = __expf(s - mx);
  float sum = blkRed<4,false>(e, sbuf);
  a2[((size_t)h * MLM + i) * MLM + j] = e / sum;
}

// ---------------- pinv init: per-head row/col sum maxima ----------------
__global__ __launch_bounds__(256)
void k_pinv_init1(const float* __restrict__ a2, float* __restrict__ hmax)
{
  __shared__ float sbuf[8];
  int h = blockIdx.x;
  int j = threadIdx.x;
  const float* A = a2 + (size_t)h * MLM * MLM;
  float cs = 0.f, rs = 0.f;
  for (int i = 0; i < MLM; i++) cs += A[i * MLM + j];
  for (int k = 0; k < MLM; k++) rs += A[j * MLM + k];
  float rmax = blkRed<4,true>(rs, sbuf);
  float cmax = blkRed<4,true>(cs, sbuf);
  if (j == 0) { hmax[h * 2] = rmax; hmax[h * 2 + 1] = cmax; }
}

// ---------------- pinv prep: a2 fp32 -> pair arrays; z0 = scal*a2^T (pairs, both layouts) ----
// scal computed inline from hmax (init2 folded in: 16 scalar loads per thread).
__global__ __launch_bounds__(256)
void k_pinv_prep(const float* __restrict__ a2, const float* __restrict__ hmax,
                 _Float16* __restrict__ a2h, _Float16* __restrict__ a2l,
                 _Float16* __restrict__ zh,  _Float16* __restrict__ zl,
                 _Float16* __restrict__ zth, _Float16* __restrict__ ztl)
{
  __shared__ float tl[64][65];
  int h = blockIdx.x >> 4, tile = blockIdx.x & 15;
  int ti = (tile >> 2) * 64, tj = (tile & 3) * 64;
  float rm = 0.f, cm = 0.f;
  #pragma unroll
  for (int hh = 0; hh < HEADS; hh++) {
    rm = fmaxf(rm, hmax[2 * hh]);
    cm = fmaxf(cm, hmax[2 * hh + 1]);
  }
  float s = 1.f / (rm * cm);
  int row = threadIdx.x >> 4, c4 = (threadIdx.x & 15) * 4;
  #pragma unroll
  for (int rr = 0; rr < 4; rr++) {
    int rloc = rr * 16 + row;
    f4 v = *(const f4*)(a2 + ((size_t)h * MLM + ti + rloc) * MLM + tj + c4);
    h4 hi, lo, zhi, zlo;
    #pragma unroll
    for (int c = 0; c < 4; c++) {
      hi[c] = (_Float16)v[c];
      lo[c] = (_Float16)(v[c] - (float)hi[c]);
      float zv = v[c] * s;
      zhi[c] = (_Float16)zv;
      zlo[c] = (_Float16)(zv - (float)zhi[c]);
      tl[rloc][c4 + c] = zv;
    }
    size_t idx = ((size_t)h * MLM + ti + rloc) * MLM + tj + c4;
    *(h4*)(a2h + idx) = hi;  *(h4*)(a2l + idx) = lo;
    *(h4*)(zth + idx) = zhi; *(h4*)(ztl + idx) = zlo;
  }
  __syncthreads();
  // z[tj+r][ti+c] = tl[c][r]
  #pragma unroll
  for (int rr = 0; rr < 4; rr++) {
    int rloc = rr * 16 + row;
    h4 hi, lo;
    #pragma unroll
    for (int c = 0; c < 4; c++) {
      float zv = tl[c4 + c][rloc];
      hi[c] = (_Float16)zv;
      lo[c] = (_Float16)(zv - (float)hi[c]);
    }
    size_t idx = ((size_t)h * MLM + tj + rloc) * MLM + ti + c4;
    *(h4*)(zh + idx) = hi; *(h4*)(zl + idx) = lo;
  }
}

// ---------------- split-fp16 pair MFMA bmm: SINGLE-WAVE blocks, zero barriers ----
// One 64-lane wave per block computes a 32(M) x 64(N) tile. gl_lds staging keeps
// the coalesced 1KB-per-issue transaction shape (R8 lesson), but the LDS dest is
// wave-uniform so NO __syncthreads is needed — only wave-local counted
// s_waitcnt vmcnt(N) (double-buffered: next tile's 12 loads stay in flight while
// current tile's MFMAs run). Same fragments, same 3-term pair-MFMA sequence,
// same K order as before -> bit-identical numerics. 256 blocks (1/CU) for the
// NS steps vs 128 4-wave barrier-locked blocks before.
__global__ __launch_bounds__(64)
void k_pbmm(const _Float16* __restrict__ Ah, const _Float16* __restrict__ Al,
            const _Float16* __restrict__ Bth, const _Float16* __restrict__ Btl,
            const _Float16* __restrict__ Eh, const _Float16* __restrict__ El,
            _Float16* __restrict__ Ch,  _Float16* __restrict__ Cl,
            _Float16* __restrict__ Cth, _Float16* __restrict__ Ctl,
            int N, float c0, float c1)
{
  __shared__ __attribute__((aligned(16))) _Float16 lds[2][6144];   // 24 KB
  int tn = N >> 6;
  int tph = 8 * tn;                       // (256/32) x (N/64) tiles per head
  int b = blockIdx.x;
  int h = b / tph, tile = b % tph;
  int bm = (tile / tn) * 32, bn = (tile % tn) * 64;
  int lane = threadIdx.x;
  int r = lane & 15, q = lane >> 4;
  int sub = lane >> 2, kq = (lane & 3) * 8;

  const _Float16* Ahb = Ah + ((size_t)h * MLM + bm) * MLM;
  const _Float16* Alb = Al + ((size_t)h * MLM + bm) * MLM;
  const _Float16* Bhb = Bth + ((size_t)h * N + bn) * MLM;
  const _Float16* Blb = Btl + ((size_t)h * N + bn) * MLM;

  const f4 zero = {0.f, 0.f, 0.f, 0.f};
  f4 acc[2][4];
  #pragma unroll
  for (int mi = 0; mi < 2; mi++)
    #pragma unroll
    for (int nj = 0; nj < 4; nj++) acc[mi][nj] = zero;

  // stage one 32-wide K-slice (12 gl_lds = A-pair 32 rows + B-pair 64 rows)
  auto stage = [&](int buf, int k0) {
    _Float16* L = &lds[buf][0];
    gl_lds(Ahb + (size_t)sub * MLM + k0 + kq,        L);
    gl_lds(Ahb + (size_t)(16 + sub) * MLM + k0 + kq, L + 512);
    gl_lds(Alb + (size_t)sub * MLM + k0 + kq,        L + 1024);
    gl_lds(Alb + (size_t)(16 + sub) * MLM + k0 + kq, L + 1536);
    #pragma unroll
    for (int c = 0; c < 4; c++)
      gl_lds(Bhb + (size_t)(c * 16 + sub) * MLM + k0 + kq, L + 2048 + c * 512);
    #pragma unroll
    for (int c = 0; c < 4; c++)
      gl_lds(Blb + (size_t)(c * 16 + sub) * MLM + k0 + kq, L + 4096 + c * 512);
  };

  stage(0, 0);
  for (int s = 0; s < 8; s++) {
    int cur = s & 1;
    if (s < 7) {
      WAVE_LDS_FENCE();                 // prior ds_reads done -> safe to overwrite other buf
      stage(1 - cur, (s + 1) * 32);
      asm volatile("s_waitcnt vmcnt(12)" ::: "memory");   // current buf's 12 loads landed
    } else {
      asm volatile("s_waitcnt vmcnt(0)" ::: "memory");
    }
    _Float16* L = &lds[cur][0];
    h8 afh[2], afl[2], bfh[4], bfl[4];
    #pragma unroll
    for (int i = 0; i < 2; i++) {
      afh[i] = *(const h8*)(L + (i * 16 + r) * 32 + q * 8);
      afl[i] = *(const h8*)(L + 1024 + (i * 16 + r) * 32 + q * 8);
    }
    #pragma unroll
    for (int j = 0; j < 4; j++) {
      bfh[j] = *(const h8*)(L + 2048 + (j * 16 + r) * 32 + q * 8);
      bfl[j] = *(const h8*)(L + 4096 + (j * 16 + r) * 32 + q * 8);
    }
    #pragma unroll
    for (int mi = 0; mi < 2; mi++)
      #pragma unroll
      for (int nj = 0; nj < 4; nj++) {
        acc[mi][nj] = __builtin_amdgcn_mfma_f32_16x16x32_f16(afh[mi], bfh[nj], acc[mi][nj], 0, 0, 0);
        acc[mi][nj] = __builtin_amdgcn_mfma_f32_16x16x32_f16(afh[mi], bfl[nj], acc[mi][nj], 0, 0, 0);
        acc[mi][nj] = __builtin_amdgcn_mfma_f32_16x16x32_f16(afl[mi], bfh[nj], acc[mi][nj], 0, 0, 0);
      }
  }
  // epilogue: straight stores + swizzled LDS transpose (Tt aliases staging buf 0)
  WAVE_LDS_FENCE();
  _Float16* Tt0 = &lds[0][0];          // [64][32] halves
  _Float16* Tt1 = &lds[0][2048];
  #pragma unroll
  for (int mi = 0; mi < 2; mi++) {
    #pragma unroll
    for (int nj = 0; nj < 4; nj++) {
      int ln = nj * 16 + r;            // local col 0..63 (N-dim)
      int X = (ln & 3) << 3;
      h4 hv, lv;
      #pragma unroll
      for (int i = 0; i < 4; i++) {
        int lm = mi * 16 + q * 4 + i;  // local row 0..31 (M-dim)
        size_t ide = ((size_t)h * MLM + bm + lm) * N + bn + ln;
        float v = c0 * acc[mi][nj][i];
        if (Eh) v += c1 * ((float)Eh[ide] + (float)El[ide]);
        _Float16 hi = (_Float16)v;
        _Float16 lo = (_Float16)(v - (float)hi);
        if (Ch) { Ch[ide] = hi; Cl[ide] = lo; }
        hv[i] = hi; lv[i] = lo;
      }
      int swb = (mi * 16 + q * 4) ^ X; // 4-aligned (X has only bits 3-4)
      *(h4*)(Tt0 + ln * 32 + swb) = hv;
      *(h4*)(Tt1 + ln * 32 + swb) = lv;
    }
  }
  WAVE_LDS_FENCE();
  {
    int row = lane;                    // 0..63 (N-dim)
    #pragma unroll
    for (int cbk = 0; cbk < 4; cbk++) {
      int cb = cbk * 8;
      int swc = cb ^ ((row & 3) << 3); // recovers elements cb..cb+7 in order
      h8 vh = *(const h8*)(Tt0 + row * 32 + swc);
      h8 vl = *(const h8*)(Tt1 + row * 32 + swc);
      size_t idt = ((size_t)h * N + bn + row) * MLM + bm + cb;
      *(h8*)(Cth + idt) = vh;
      *(h8*)(Ctl + idt) = vl;
    }
  }
}

// ---------------- flash attn3: partials of softmax(ql @ k^T) @ v ----------------
// Defer-max online softmax (T13).
__global__ __launch_bounds__(256)
void k_attn3(const _Float16* __restrict__ ql16, const _Float16* __restrict__ k16,
             const _Float16* __restrict__ vt16,
             float* __restrict__ pm, float* __restrict__ ps, float* __restrict__ pacc)
{
  __shared__ __attribute__((aligned(16))) _Float16 Pl[4][64 * 40];
  int c = blockIdx.x, h = blockIdx.y;
  int tid = threadIdx.x, lane = tid & 63, w = tid >> 6;
  int r = lane & 15, q = lane >> 4;
  int t0 = c * PER;
  int m0 = w * 64;
  const _Float16* qlh = ql16 + (size_t)h * MLM * 64;
  const _Float16* kh  = k16  + (size_t)h * NSEQP * 64;
  const _Float16* vh  = vt16 + (size_t)h * 64 * NSEQP;
  _Float16* Pw = &Pl[w][0];

  h8 af[4][2];
  #pragma unroll
  for (int mt = 0; mt < 4; mt++)
    #pragma unroll
    for (int ks = 0; ks < 2; ks++)
      af[mt][ks] = *(const h8*)(qlh + (size_t)(m0 + mt * 16 + r) * 64 + ks * 32 + q * 8);

  const f4 zero = {0.f, 0.f, 0.f, 0.f};
  f4 acc[4][4];
  float mrun[4][4], lrun[4][4];
  #pragma unroll
  for (int mt = 0; mt < 4; mt++) {
    #pragma unroll
    for (int nd = 0; nd < 4; nd++) acc[mt][nd] = zero;
    #pragma unroll
    for (int i = 0; i < 4; i++) { mrun[mt][i] = -1e30f; lrun[mt][i] = 0.f; }
  }

  for (int tb = 0; tb < 20; tb++) {
    int tt = t0 + tb * 32;
    f4 S[4][2];
    #pragma unroll
    for (int mt = 0; mt < 4; mt++) { S[mt][0] = zero; S[mt][1] = zero; }
    #pragma unroll
    for (int nt = 0; nt < 2; nt++) {
      h8 b0 = *(const h8*)(kh + (size_t)(tt + nt * 16 + r) * 64 + q * 8);
      h8 b1 = *(const h8*)(kh + (size_t)(tt + nt * 16 + r) * 64 + 32 + q * 8);
      #pragma unroll
      for (int mt = 0; mt < 4; mt++) {
        S[mt][nt] = __builtin_amdgcn_mfma_f32_16x16x32_f16(af[mt][0], b0, S[mt][nt], 0, 0, 0);
        S[mt][nt] = __builtin_amdgcn_mfma_f32_16x16x32_f16(af[mt][1], b1, S[mt][nt], 0, 0, 0);
      }
    }
    if (tb == 19) {
      #pragma unroll
      for (int nt = 0; nt < 2; nt++) {
        bool valid = (tb * 32 + nt * 16 + r) < PER;
        #pragma unroll
        for (int mt = 0; mt < 4; mt++)
          #pragma unroll
          for (int i = 0; i < 4; i++)
            S[mt][nt][i] = valid ? S[mt][nt][i] : -1e30f;
      }
    }
    #pragma unroll
    for (int mt = 0; mt < 4; mt++) {
      bool tg = false;
      #pragma unroll
      for (int i = 0; i < 4; i++)
        tg = tg || (S[mt][0][i] > mrun[mt][i] + 8.f) || (S[mt][1][i] > mrun[mt][i] + 8.f);
      if (__any(tg)) {
        float nm[4], al[4];
        #pragma unroll
        for (int i = 0; i < 4; i++) {
          nm[i] = fmaxf(S[mt][0][i], S[mt][1][i]);
          #pragma unroll
          for (int o = 1; o < 16; o <<= 1) nm[i] = fmaxf(nm[i], __shfl_xor(nm[i], o, 64));
          nm[i] = fmaxf(nm[i], mrun[mt][i]);
          al[i] = __expf(mrun[mt][i] - nm[i]);
          mrun[mt][i] = nm[i];
          lrun[mt][i] *= al[i];
        }
        #pragma unroll
        for (int nd = 0; nd < 4; nd++)
          #pragma unroll
          for (int i = 0; i < 4; i++) acc[mt][nd][i] *= al[i];
      }
      #pragma unroll
      for (int i = 0; i < 4; i++) {
        float p0 = __expf(S[mt][0][i] - mrun[mt][i]);
        float p1 = __expf(S[mt][1][i] - mrun[mt][i]);
        lrun[mt][i] += p0 + p1;
        S[mt][0][i] = p0; S[mt][1][i] = p1;
      }
      #pragma unroll
      for (int nt = 0; nt < 2; nt++)
        #pragma unroll
        for (int i = 0; i < 4; i++)
          Pw[(mt * 16 + q * 4 + i) * 40 + nt * 16 + r] = (_Float16)S[mt][nt][i];
    }
    WAVE_LDS_FENCE();
    h8 bv[4];
    #pragma unroll
    for (int nd = 0; nd < 4; nd++)
      bv[nd] = *(const h8*)(vh + (size_t)(nd * 16 + r) * NSEQP + tt + q * 8);
    #pragma unroll
    for (int mt = 0; mt < 4; mt++) {
      h8 ap = *(const h8*)(Pw + (mt * 16 + r) * 40 + q * 8);
      #pragma unroll
      for (int nd = 0; nd < 4; nd++)
        acc[mt][nd] = __builtin_amdgcn_mfma_f32_16x16x32_f16(ap, bv[nd], acc[mt][nd], 0, 0, 0);
    }
    WAVE_LDS_FENCE();
  }
  // finalize the deferred row-sum (one butterfly over the 16 r-lanes)
  #pragma unroll
  for (int mt = 0; mt < 4; mt++)
    #pragma unroll
    for (int i = 0; i < 4; i++)
      #pragma unroll
      for (int o = 1; o < 16; o <<= 1) lrun[mt][i] += __shfl_xor(lrun[mt][i], o, 64);
  int cidx = h * CHUNKS + c;
  #pragma unroll
  for (int mt = 0; mt < 4; mt++) {
    int rowb = m0 + mt * 16 + q * 4;
    if (r == 0) {
      #pragma unroll
      for (int i = 0; i < 4; i++) {
        pm[(size_t)cidx * MLM + rowb + i] = mrun[mt][i];
        ps[(size_t)cidx * MLM + rowb + i] = lrun[mt][i];
      }
    }
    #pragma unroll
    for (int nd = 0; nd < 4; nd++)
      #pragma unroll
      for (int i = 0; i < 4; i++)
        pacc[((size_t)cidx * MLM + rowb + i) * 64 + nd * 16 + r] = acc[mt][nd][i];
  }
}

// reduce partials -> avT pairs [h][64][256]
__global__ __launch_bounds__(64)
void k_attn3_reduce(const float* __restrict__ pm, const float* __restrict__ ps,
                    const float* __restrict__ pacc,
                    _Float16* __restrict__ avth, _Float16* __restrict__ avtl)
{
  int h = blockIdx.x >> 8, i = blockIdx.x & 255;
  int d = threadIdx.x;
  float m = -1e30f;
  for (int c = 0; c < CHUNKS; c++) m = fmaxf(m, pm[(h * CHUNKS + c) * MLM + i]);
  float l = 0.f, a = 0.f;
  for (int c = 0; c < CHUNKS; c++) {
    int idx = (h * CHUNKS + c) * MLM + i;
    float w = __expf(pm[idx] - m);
    l += ps[idx] * w;
    a += pacc[(size_t)idx * DH + d] * w;
  }
  float v = a / l;
  _Float16 hi = (_Float16)v;
  size_t o = ((size_t)h * DH + d) * MLM + i;
  avth[o] = hi;
  avtl[o] = (_Float16)(v - (float)hi);
}

// ---------------- depthwise 33-tap conv on v -> xat16 ----------------
__global__ __launch_bounds__(256)
void k_conv(const _Float16* __restrict__ v16, const float* __restrict__ rw,
            _Float16* __restrict__ xat)
{
  __shared__ float tl[160][64];
  int h = blockIdx.y;
  int t0 = PADF + blockIdx.x * 128;
  for (int c = threadIdx.x; c < 160 * 16; c += 256) {
    int row = c >> 4, d4 = (c & 15) * 4;
    int ts = t0 - 16 + row;
    f4 val = {0.f, 0.f, 0.f, 0.f};
    if (ts >= 0 && ts < NSEQ) {
      h4 hv = *(const h4*)(v16 + ((size_t)h * NSEQP + ts) * 64 + d4);
      val[0] = (float)hv[0]; val[1] = (float)hv[1]; val[2] = (float)hv[2]; val[3] = (float)hv[3];
    }
    *(f4*)&tl[row][d4] = val;
  }
  __syncthreads();
  float wt[33];
  #pragma unroll
  for (int tap = 0; tap < 33; tap++) wt[tap] = rw[h * 33 + tap];
  int d4 = (threadIdx.x & 15) * 4, r0 = threadIdx.x >> 4;
  #pragma unroll
  for (int k = 0; k < 8; k++) {
    int r = k * 16 + r0;
    int t = t0 + r;
    f4 acc = {0.f, 0.f, 0.f, 0.f};
    #pragma unroll
    for (int tap = 0; tap < 33; tap++) {
      f4 vv = *(const f4*)&tl[r + tap][d4];
      acc[0] += wt[tap] * vv[0]; acc[1] += wt[tap] * vv[1];
      acc[2] += wt[tap] * vv[2]; acc[3] += wt[tap] * vv[3];
    }
    if (t < NSEQ) {
      h4 o = {(_Float16)acc[0], (_Float16)acc[1], (_Float16)acc[2], (_Float16)acc[3]};
      *(h4*)(xat + (size_t)t * DIMC + h * 64 + d4) = o;
    }
  }
}

// ---------------- flash attn1: xat += softmax(q @ kl^T) @ w2, attn3-style ----------------
// Block = 256 q-rows x 1 head (4 waves x 64 rows). Defer-max online softmax (T13).
__global__ __launch_bounds__(256)
void k_attn1(const _Float16* __restrict__ q16, const _Float16* __restrict__ kl16,
             const _Float16* __restrict__ w2t16, _Float16* __restrict__ xat)
{
  __shared__ __attribute__((aligned(16))) _Float16 Pl[4][64 * 40];   // P tile; reused as output staging
  int h = blockIdx.y;
  int t0 = blockIdx.x * 256;            // 157 * 256 = NSEQ exactly
  int tid = threadIdx.x, lane = tid & 63, w = tid >> 6;
  int r = lane & 15, q = lane >> 4;
  int m0 = w * 64;
  const _Float16* qh  = q16  + (size_t)h * NSEQP * 64;
  const _Float16* klh = kl16 + (size_t)h * MLM * 64;
  const _Float16* w2h = w2t16 + (size_t)h * 64 * 256;
  _Float16* Pw = &Pl[w][0];

  h8 af[4][2];
  #pragma unroll
  for (int mt = 0; mt < 4; mt++)
    #pragma unroll
    for (int ks = 0; ks < 2; ks++)
      af[mt][ks] = *(const h8*)(qh + (size_t)(t0 + m0 + mt * 16 + r) * 64 + ks * 32 + q * 8);

  const f4 zero = {0.f, 0.f, 0.f, 0.f};
  f4 acc[4][4];
  float mrun[4][4], lrun[4][4];
  #pragma unroll
  for (int mt = 0; mt < 4; mt++) {
    #pragma unroll
    for (int nd = 0; nd < 4; nd++) acc[mt][nd] = zero;
    #pragma unroll
    for (int i = 0; i < 4; i++) { mrun[mt][i] = -1e30f; lrun[mt][i] = 0.f; }
  }

  for (int tb = 0; tb < 8; tb++) {      // 8 tiles x 32 landmarks = 256
    int tt = tb * 32;
    f4 S[4][2];
    #pragma unroll
    for (int mt = 0; mt < 4; mt++) { S[mt][0] = zero; S[mt][1] = zero; }
    #pragma unroll
    for (int nt = 0; nt < 2; nt++) {
      h8 b0 = *(const h8*)(klh + (size_t)(tt + nt * 16 + r) * 64 + q * 8);
      h8 b1 = *(const h8*)(klh + (size_t)(tt + nt * 16 + r) * 64 + 32 + q * 8);
      #pragma unroll
      for (int mt = 0; mt < 4; mt++) {
        S[mt][nt] = __builtin_amdgcn_mfma_f32_16x16x32_f16(af[mt][0], b0, S[mt][nt], 0, 0, 0);
        S[mt][nt] = __builtin_amdgcn_mfma_f32_16x16x32_f16(af[mt][1], b1, S[mt][nt], 0, 0, 0);
      }
    }
    #pragma unroll
    for (int mt = 0; mt < 4; mt++) {
      bool tg = false;
      #pragma unroll
      for (int i = 0; i < 4; i++)
        tg = tg || (S[mt][0][i] > mrun[mt][i] + 8.f) || (S[mt][1][i] > mrun[mt][i] + 8.f);
      if (__any(tg)) {
        float nm[4], al[4];
        #pragma unroll
        for (int i = 0; i < 4; i++) {
          nm[i] = fmaxf(S[mt][0][i], S[mt][1][i]);
          #pragma unroll
          for (int o = 1; o < 16; o <<= 1) nm[i] = fmaxf(nm[i], __shfl_xor(nm[i], o, 64));
          nm[i] = fmaxf(nm[i], mrun[mt][i]);
          al[i] = __expf(mrun[mt][i] - nm[i]);
          mrun[mt][i] = nm[i];
          lrun[mt][i] *= al[i];
        }
        #pragma unroll
        for (int nd = 0; nd < 4; nd++)
          #pragma unroll
          for (int i = 0; i < 4; i++) acc[mt][nd][i] *= al[i];
      }
      #pragma unroll
      for (int i = 0; i < 4; i++) {
        float p0 = __expf(S[mt][0][i] - mrun[mt][i]);
        float p1 = __expf(S[mt][1][i] - mrun[mt][i]);
        lrun[mt][i] += p0 + p1;
        S[mt][0][i] = p0; S[mt][1][i] = p1;
      }
      #pragma unroll
      for (int nt = 0; nt < 2; nt++)
        #pragma unroll
        for (int i = 0; i < 4; i++)
          Pw[(mt * 16 + q * 4 + i) * 40 + nt * 16 + r] = (_Float16)S[mt][nt][i];
    }
    WAVE_LDS_FENCE();
    h8 bw[4];
    #pragma unroll
    for (int nd = 0; nd < 4; nd++)
      bw[nd] = *(const h8*)(w2h + (size_t)(nd * 16 + r) * 256 + tt + q * 8);
    #pragma unroll
    for (int mt = 0; mt < 4; mt++) {
      h8 ap = *(const h8*)(Pw + (mt * 16 + r) * 40 + q * 8);
      #pragma unroll
      for (int nd = 0; nd < 4; nd++)
        acc[mt][nd] = __builtin_amdgcn_mfma_f32_16x16x32_f16(ap, bw[nd], acc[mt][nd], 0, 0, 0);
    }
    WAVE_LDS_FENCE();
  }
  // finalize the deferred row-sum
  #pragma unroll
  for (int mt = 0; mt < 4; mt++)
    #pragma unroll
    for (int i = 0; i < 4; i++)
      #pragma unroll
      for (int o = 1; o < 16; o <<= 1) lrun[mt][i] += __shfl_xor(lrun[mt][i], o, 64);
  // normalize + add into xat, via per-wave LDS transpose (two 32-row halves)
  #pragma unroll
  for (int half = 0; half < 2; half++) {
    #pragma unroll
    for (int mt2 = 0; mt2 < 2; mt2++) {
      int mt = half * 2 + mt2;
      float li[4];
      #pragma unroll
      for (int i = 0; i < 4; i++) li[i] = 1.f / lrun[mt][i];
      #pragma unroll
      for (int nd = 0; nd < 4; nd++)
        #pragma unroll
        for (int i = 0; i < 4; i++)
          Pw[(mt2 * 16 + q * 4 + i) * 72 + nd * 16 + r] = (_Float16)(acc[mt][nd][i] * li[i]);
    }
    WAVE_LDS_FENCE();
    #pragma unroll
    for (int c = 0; c < 4; c++) {
      int row = c * 8 + (lane >> 3);    // 0..31
      int ch = (lane & 7) * 8;
      int t = t0 + m0 + half * 32 + row;
      if (t >= PADF) {
        _Float16* dst = xat + (size_t)t * DIMC + h * 64 + ch;
        h8 cv = *(h8*)dst;
        h8 pv = *(const h8*)(Pw + row * 72 + ch);
        h8 o;
        #pragma unroll
        for (int k = 0; k < 8; k++) o[k] = (_Float16)((float)cv[k] + (float)pv[k]);
        *(h8*)dst = o;
      }
    }
    WAVE_LDS_FENCE();                   // WAR before next half reuses Pw
  }
}

// ---------------- PPEG ----------------
__global__ __launch_bounds__(256)
void k_transpose_fw(const float* __restrict__ h, float* __restrict__ g)
{
  __shared__ float tile[32][33];
  int pb = blockIdx.x * 32, cb = blockIdx.y * 32;
  int x = threadIdx.x & 31, y0 = threadIdx.x >> 5;
  #pragma unroll
  for (int yy = y0; yy < 32; yy += 8)
    tile[yy][x] = h[(size_t)(1 + pb + yy) * DIMC + cb + x];
  __syncthreads();
  #pragma unroll
  for (int yy = y0; yy < 32; yy += 8)
    g[(size_t)(cb + yy) * NPATCH + pb + x] = tile[x][yy];
}

// 32x32 output tile, 2 channels/block packed as float2 (-> v_pk_fma_f32).
__global__ __launch_bounds__(256)
void k_ppeg(const float* __restrict__ g,
            const float* __restrict__ w7, const float* __restrict__ b7,
            const float* __restrict__ w5, const float* __restrict__ b5,
            const float* __restrict__ w3, const float* __restrict__ b3,
            float* __restrict__ o)
{
  __shared__ f2 tl[38][40];             // 12.2 KB
  int cp = blockIdx.y;
  int c0 = cp * 2, c1 = c0 + 1;
  int ty0 = (blockIdx.x / 7) * 32, tx0 = (blockIdx.x % 7) * 32;
  const float* g0 = g + (size_t)c0 * NPATCH;
  const float* g1 = g + (size_t)c1 * NPATCH;
  for (int e = threadIdx.x; e < 38 * 40; e += 256) {
    int row = e / 40, col = e % 40;
    int y = ty0 - 3 + row, x = tx0 - 3 + col;
    f2 v = {0.f, 0.f};
    if (y >= 0 && y < GRID && x >= 0 && x < GRID && col < 38) {
      v[0] = g0[y * GRID + x];
      v[1] = g1[y * GRID + x];
    }
    tl[row][col] = v;
  }
  __syncthreads();
  int tx4 = (threadIdx.x & 7) * 4, ty = threadIdx.x >> 3;   // 32 rows x 8 col-groups
  f2 bb = {b7[c0] + b5[c0] + b3[c0], b7[c1] + b5[c1] + b3[c1]};
  f2 acc[4];
  #pragma unroll
  for (int j = 0; j < 4; j++) acc[j] = bb + tl[ty + 3][tx4 + 3 + j];
  #pragma unroll
  for (int ky = 0; ky < 7; ky++) {
    f2 f[10];
    #pragma unroll
    for (int k = 0; k < 5; k++)
      *(f4*)&f[k * 2] = *(const f4*)&tl[ty + ky][tx4 + k * 2];
    #pragma unroll
    for (int kx = 0; kx < 7; kx++) {
      f2 wv = {w7[c0 * 49 + ky * 7 + kx], w7[c1 * 49 + ky * 7 + kx]};
      #pragma unroll
      for (int j = 0; j < 4; j++) acc[j] += wv * f[kx + j];
    }
    if (ky >= 1 && ky <= 5) {
      #pragma unroll
      for (int kx = 0; kx < 5; kx++) {
        f2 wv = {w5[c0 * 25 + (ky - 1) * 5 + kx], w5[c1 * 25 + (ky - 1) * 5 + kx]};
        #pragma unroll
        for (int j = 0; j < 4; j++) acc[j] += wv * f[1 + kx + j];
      }
    }
    if (ky >= 2 && ky <= 4) {
      #pragma unroll
      for (int kx = 0; kx < 3; kx++) {
        f2 wv = {w3[c0 * 9 + (ky - 2) * 3 + kx], w3[c1 * 9 + (ky - 2) * 3 + kx]};
        #pragma unroll
        for (int j = 0; j < 4; j++) acc[j] += wv * f[2 + kx + j];
      }
    }
  }
  int y = ty0 + ty, xb = tx0 + tx4;
  if (y < GRID && xb < GRID) {
    f4 o0 = {acc[0][0], acc[1][0], acc[2][0], acc[3][0]};
    f4 o1 = {acc[0][1], acc[1][1], acc[2][1], acc[3][1]};
    *(f4*)(o + (size_t)c0 * NPATCH + y * GRID + xb) = o0;
    *(f4*)(o + (size_t)c1 * NPATCH + y * GRID + xb) = o1;
  }
}

__global__ __launch_bounds__(256)
void k_transpose_bw(const float* __restrict__ g, float* __restrict__ h)
{
  __shared__ float tile[32][33];
  int pb = blockIdx.x * 32, cb = blockIdx.y * 32;
  int x = threadIdx.x & 31, y0 = threadIdx.x >> 5;
  #pragma unroll
  for (int yy = y0; yy < 32; yy += 8)
    tile[yy][x] = g[(size_t)(cb + yy) * NPATCH + pb + x];
  __syncthreads();
  #pragma unroll
  for (int yy = y0; yy < 32; yy += 8)
    h[(size_t)(1 + pb + yy) * DIMC + cb + x] = tile[x][yy];
}

// ---------------- final: layernorm(row 0) @ fc2 ----------------
__global__ __launch_bounds__(512)
void k_final(const float* __restrict__ h, const float* __restrict__ nw, const float* __restrict__ nb,
             const float* __restrict__ fw, const float* __restrict__ fb, float* __restrict__ out)
{
  __shared__ float sbuf[8];
  int d = threadIdx.x;
  float x = h[d];
  float mu = blkRed<8,false>(x, sbuf) * (1.f / 512.f);
  float dd = x - mu;
  float var = blkRed<8,false>(dd * dd, sbuf) * (1.f / 512.f);
  float cls = dd * rsqrtf(var + 1e-5f) * nw[d] + nb[d];
  float l0 = blkRed<8,false>(cls * fw[d * 2 + 0], sbuf);
  float l1 = blkRed<8,false>(cls * fw[d * 2 + 1], sbuf);
  if (d == 0) { out[0] = l0 + fb[0]; out[1] = l1 + fb[1]; }
}

// ---------------- host orchestration ----------------
struct Pair4 { _Float16 *h, *l, *th, *tl; };
struct WsPtrs {
  float *h, *ql, *kl, *a2, *hmax, *scal, *pm, *ps, *pacc;
  _Float16 *xat16, *q16, *k16, *v16, *vt16, *ql16, *kl16, *x16;
  _Float16 *a2h, *a2l, *avth, *avtl;
  Pair4 zA, zB, xz, u, u2, w2;
};

static void attention_layer(const WsPtrs& P,
                            const float* nw, const float* nb, const _Float16* qkvw16,
                            const _Float16* ow16, const float* ob, const float* rw,
                            hipStream_t stream)
{
  k_zpad<<<64, 256, 0, stream>>>(P.q16, P.k16, P.v16);
  k_ln_pad<<<NSEQ, 256, 0, stream>>>(P.h, nw, nb, P.xat16);
  k_gemm16<<<dim3((NSEQ / 128) * (1536 / 128)), 256, 0, stream>>>(
      P.xat16, qkvw16, nullptr, nullptr, P.q16, P.k16, P.v16, NSEQ, DIMC, 3 * DIMC, 4);
  k_vt<<<dim3(629, HEADS), 256, 0, stream>>>(P.v16, P.vt16);
  k_landmarks<<<HEADS * MLM, 256, 0, stream>>>(P.q16, P.k16, P.ql, P.kl, P.ql16, P.kl16);
  k_attn2<<<HEADS * MLM, 256, 0, stream>>>(P.ql, P.kl, P.a2);
  k_pinv_init1<<<HEADS, 256, 0, stream>>>(P.a2, P.hmax);
  k_pinv_prep<<<HEADS * 16, 256, 0, stream>>>(P.a2, P.hmax,
      P.a2h, P.a2l, P.zA.h, P.zA.l, P.zA.th, P.zA.tl);
  Pair4 z = P.zA, zn = P.zB;
  for (int it = 0; it < 6; it++) {
    // single-wave pbmm: grid = HEADS * (256/32) * (N/64) blocks of 64 threads
    k_pbmm<<<dim3(HEADS * 8 * (MLM >> 6)), 64, 0, stream>>>(P.a2h, P.a2l, z.th, z.tl,
        nullptr, nullptr, P.xz.h, P.xz.l, P.xz.th, P.xz.tl, MLM, 1.f, 0.f);
    // u and u2 are consumed ONLY in transposed layout -> skip straight stores
    k_pbmm<<<dim3(HEADS * 8 * (MLM >> 6)), 64, 0, stream>>>(P.xz.h, P.xz.l, P.xz.th, P.xz.tl,
        P.xz.h, P.xz.l, nullptr, nullptr, P.u.th, P.u.tl, MLM, -1.f, 7.f);
    k_pbmm<<<dim3(HEADS * 8 * (MLM >> 6)), 64, 0, stream>>>(P.xz.h, P.xz.l, P.u.th, P.u.tl,
        P.xz.h, P.xz.l, nullptr, nullptr, P.u2.th, P.u2.tl, MLM, -1.f, 15.f);
    k_pbmm<<<dim3(HEADS * 8 * (MLM >> 6)), 64, 0, stream>>>(z.h, z.l, P.u2.th, P.u2.tl,
        z.h, z.l, zn.h, zn.l, zn.th, zn.tl, MLM, -0.25f, 3.25f);
    Pair4 t = z; z = zn; zn = t;
  }
  k_attn3<<<dim3(CHUNKS, HEADS), 256, 0, stream>>>(P.ql16, P.k16, P.vt16, P.pm, P.ps, P.pacc);
  k_attn3_reduce<<<HEADS * MLM, 64, 0, stream>>>(P.pm, P.ps, P.pacc, P.avth, P.avtl);
  // w2 = z @ av ; only w2^T (hi/lo) is consumed by attn1 -> skip straight stores
  k_pbmm<<<dim3(HEADS * 8 * (DH >> 6)), 64, 0, stream>>>(z.h, z.l, P.avth, P.avtl,
      nullptr, nullptr, nullptr, nullptr, P.w2.th, P.w2.tl, DH, 1.f, 0.f);
  k_conv<<<dim3(313, HEADS), 256, 0, stream>>>(P.v16, rw, P.xat16);
  k_attn1<<<dim3(157, HEADS), 256, 0, stream>>>(P.q16, P.kl16, P.w2.th, P.xat16);
  k_gemm16<<<dim3(((NTOK + 127) / 128) * (DIMC / 128)), 256, 0, stream>>>(
      P.xat16 + (size_t)PADF * DIMC, ow16, ob, P.h, nullptr, nullptr, nullptr, NTOK, DIMC, DIMC, 2);
}

extern "C" void kernel_launch(void* const* d_in, const int* in_sizes, int n_in,
                              void* d_out, int out_size, void* d_ws, size_t ws_size,
                              hipStream_t stream)
{
  const float* x      = (const float*)d_in[0];
  const float* fc1_w  = (const float*)d_in[1];
  const float* fc1_b  = (const float*)d_in[2];
  const float* cls    = (const float*)d_in[3];
  const float* l1_nw  = (const float*)d_in[4];
  const float* l1_nb  = (const float*)d_in[5];
  const float* l1_qkv = (const float*)d_in[6];
  const float* l1_ow  = (const float*)d_in[7];
  const float* l1_ob  = (const float*)d_in[8];
  const float* l1_rw  = (const float*)d_in[9];
  const float* p7w    = (const float*)d_in[10];
  const float* p7b    = (const float*)d_in[11];
  const float* p5w    = (const float*)d_in[12];
  const float* p5b    = (const float*)d_in[13];
  const float* p3w    = (const float*)d_in[14];
  const float* p3b    = (const float*)d_in[15];
  const float* l2_nw  = (const float*)d_in[16];
  const float* l2_nb  = (const float*)d_in[17];
  const float* l2_qkv = (const float*)d_in[18];
  const float* l2_ow  = (const float*)d_in[19];
  const float* l2_ob  = (const float*)d_in[20];
  const float* l2_rw  = (const float*)d_in[21];
  const float* nw     = (const float*)d_in[22];
  const float* nb     = (const float*)d_in[23];
  const float* fc2w   = (const float*)d_in[24];
  const float* fc2b   = (const float*)d_in[25];
  float* out = (float*)d_out;

  // ---- workspace carve-up (float offsets) ----
  float* W = (float*)d_ws;
  WsPtrs P;
  size_t off = 0;
  P.h     = W + off;               off += 20480512ull;   // 40001 x 512 fp32
  P.xat16 = (_Float16*)(W + off);  off += 10289152ull;   // NSEQ x 512 fp16
  float* R0 = W + off;                                   // fp16 q/k/v/vt region
  P.q16   = (_Float16*)R0;
  P.k16   = P.q16 + 20594688ull;   // 8 x 40224 x 64
  P.v16   = P.k16 + 20594688ull;
  P.vt16  = P.v16 + 20594688ull;   // 8 x 64 x 40224
  P.x16   = P.q16;                 // alias: fc1 input fp16 (dead before qkv GEMM)
  off += 41189376ull;              // 4 x 20594688 halfs / 2
  P.ql    = W + off; off += 131072;
  P.kl    = W + off; off += 131072;
  P.ql16  = (_Float16*)(W + off); off += 65536;
  P.kl16  = (_Float16*)(W + off); off += 65536;
  P.a2    = W + off; off += 524288;
  // fp16 pair region for pinv (sizes in halves -> float offsets are /2)
  _Float16* HP = (_Float16*)(W + off);
  size_t ho = 0;
  P.a2h = HP + ho; ho += 524288; P.a2l = HP + ho; ho += 524288;
  auto alloc4 = [&](Pair4& p, size_t n) {
    p.h = HP + ho; ho += n; p.l = HP + ho; ho += n;
    p.th = HP + ho; ho += n; p.tl = HP + ho; ho += n;
  };
  alloc4(P.zA, 524288); alloc4(P.zB, 524288); alloc4(P.xz, 524288);
  alloc4(P.u, 524288);  alloc4(P.u2, 524288);
  alloc4(P.w2, 131072);
  P.avth = HP + ho; ho += 131072; P.avtl = HP + ho; ho += 131072;
  off += (ho + 1) / 2;
  P.hmax  = W + off; P.scal = P.hmax + 16; off += 32;
  P.pm    = W + off; off += 131072;
  P.ps    = W + off; off += 131072;
  P.pacc  = W + off; off += 8388608;
  _Float16* fc1t  = (_Float16*)(W + off);   // 512x1024
  _Float16* qkv1t = fc1t  + 524288;         // 1536x512
  _Float16* out1t = qkv1t + 786432;         // 512x512
  _Float16* qkv2t = out1t + 262144;
  _Float16* out2t = qkv2t + 786432;

  // ---- weight fp32 -> fp16 transposed (N x K) ----
  k_wt16<<<dim3(INDIM / 32, DIMC / 32), 256, 0, stream>>>(fc1_w, fc1t, INDIM, DIMC);
  k_wt16<<<dim3(DIMC / 32, 1536 / 32), 256, 0, stream>>>(l1_qkv, qkv1t, DIMC, 1536);
  k_wt16<<<dim3(DIMC / 32, DIMC / 32), 256, 0, stream>>>(l1_ow, out1t, DIMC, DIMC);
  k_wt16<<<dim3(DIMC / 32, 1536 / 32), 256, 0, stream>>>(l2_qkv, qkv2t, DIMC, 1536);
  k_wt16<<<dim3(DIMC / 32, DIMC / 32), 256, 0, stream>>>(l2_ow, out2t, DIMC, DIMC);

  // fc1 + relu -> h rows 1..40000 ; cls token -> h row 0
  k_f32_to_f16<<<NPATCH * INDIM / 1024, 256, 0, stream>>>(x, P.x16);
  k_gemm16<<<dim3(((NPATCH + 127) / 128) * (DIMC / 128)), 256, 0, stream>>>(
      P.x16, fc1t, fc1_b, P.h + DIMC, nullptr, nullptr, nullptr, NPATCH, INDIM, DIMC, 1);
  k_set_cls<<<1, 512, 0, stream>>>(cls, P.h);

  // layer 1 attention
  attention_layer(P, l1_nw, l1_nb, qkv1t, out1t, l1_ob, l1_rw, stream);

  // PPEG (aliases the q/k/v fp16 region as fp32 scratch)
  float* fgrid = R0;
  float* cout  = R0 + 20480000ull;
  k_transpose_fw<<<dim3(NPATCH / 32, DIMC / 32), 256, 0, stream>>>(P.h, fgrid);
  k_ppeg<<<dim3(7 * 7, DIMC / 2), 256, 0, stream>>>(fgrid, p7w, p7b, p5w, p5b, p3w, p3b, cout);
  k_transpose_bw<<<dim3(NPATCH / 32, DIMC / 32), 256, 0, stream>>>(cout, P.h);

  // layer 2 attention
  attention_layer(P, l2_nw, l2_nb, qkv2t, out2t, l2_ob, l2_rw, stream);

  // final layernorm (cls row only) + fc2
  k_final<<<1, 512, 0, stream>>>(P.h, nw, nb, fc2w, fc2b, out);
}

// Round 11
// 2087.773 us; speedup vs baseline: 1.0516x; 1.0516x over previous
//
#include <hip/hip_runtime.h>
#include <hip/hip_bf16.h>

// ---------------- problem constants ----------------
#define DIMC   512
#define HEADS  8
#define DH     64
#define MLM    256          // landmarks
#define NPATCH 40000
#define NTOK   40001        // with cls
#define PADF   191          // front zero pad
#define NSEQ   40192        // NTOK + PADF
#define NSEQP  40224        // NSEQ + 32 (zero pad for flash tiles)
#define LWIN   157          // NSEQ / MLM
#define INDIM  1024
#define GRID   200
#define CHUNKS 64
#define PER    628          // NSEQ / CHUNKS

typedef _Float16 h8 __attribute__((ext_vector_type(8)));
typedef _Float16 h4 __attribute__((ext_vector_type(4)));
typedef float    f4 __attribute__((ext_vector_type(4)));
typedef float    f2 __attribute__((ext_vector_type(2)));

// wave-local ordering fence: DS ops from one wave complete in order; this
// stops the COMPILER from reordering LDS ops across the point and drains
// outstanding LDS returns. Much cheaper than __syncthreads for per-wave LDS.
// NOTE: "memory" clobber also pins GLOBAL loads -> independent next-tile loads
// must be ISSUED (in source order) before the fence to pipeline across it.
#define WAVE_LDS_FENCE() asm volatile("s_waitcnt lgkmcnt(0)" ::: "memory")

// async global->LDS, 16B per lane; LDS dest = wave-uniform base + lane*16
__device__ __forceinline__ void gl_lds(const _Float16* g, _Float16* l) {
  __builtin_amdgcn_global_load_lds(
      (const __attribute__((address_space(1))) void*)g,
      (__attribute__((address_space(3))) void*)l, 16, 0, 0);
}

// ---------------- reductions ----------------
template<int NW, bool ISMAX>
__device__ __forceinline__ float blkRed(float v, float* s) {
  #pragma unroll
  for (int o = 32; o; o >>= 1) {
    float t = __shfl_down(v, o, 64);
    v = ISMAX ? fmaxf(v, t) : v + t;
  }
  int lane = threadIdx.x & 63, w = threadIdx.x >> 6;
  __syncthreads();
  if (lane == 0) s[w] = v;
  __syncthreads();
  float r = s[0];
  #pragma unroll
  for (int i = 1; i < NW; i++) r = ISMAX ? fmaxf(r, s[i]) : r + s[i];
  return r;
}

// ---------------- misc small kernels ----------------
__global__ __launch_bounds__(512)
void k_set_cls(const float* __restrict__ cls, float* __restrict__ h) {
  h[threadIdx.x] = cls[threadIdx.x];
}

__global__ __launch_bounds__(256)
void k_f32_to_f16(const float* __restrict__ in, _Float16* __restrict__ out) {
  int i = blockIdx.x * 256 + threadIdx.x;
  float4 v = ((const float4*)in)[i];
  h4 o = {(_Float16)v.x, (_Float16)v.y, (_Float16)v.z, (_Float16)v.w};
  *(h4*)(out + (size_t)i * 4) = o;
}

// zero the 32-row pads of q16/k16/v16 (8 heads x 32 rows x 64)
__global__ __launch_bounds__(256)
void k_zpad(_Float16* q16, _Float16* k16, _Float16* v16) {
  int idx = blockIdx.x * 256 + threadIdx.x;       // 16384 total
  int h = idx >> 11, r = (idx >> 6) & 31, d = idx & 63;
  size_t a = ((size_t)h * NSEQP + NSEQ + r) * 64 + d;
  q16[a] = (_Float16)0.f; k16[a] = (_Float16)0.f; v16[a] = (_Float16)0.f;
}

// weight K x N fp32 -> transposed N x K fp16
__global__ __launch_bounds__(256)
void k_wt16(const float* __restrict__ B, _Float16* __restrict__ Bt, int K, int N)
{
  __shared__ float tile[32][33];
  int kb = blockIdx.x * 32, nb = blockIdx.y * 32;
  int x = threadIdx.x & 31, y0 = threadIdx.x >> 5;
  #pragma unroll
  for (int yy = y0; yy < 32; yy += 8)
    tile[yy][x] = B[(size_t)(kb + yy) * N + nb + x];
  __syncthreads();
  #pragma unroll
  for (int yy = y0; yy < 32; yy += 8)
    Bt[(size_t)(nb + yy) * K + kb + x] = (_Float16)tile[x][yy];
}

// ---------------- fp16 MFMA GEMM: 128x128 tile, swapped-operand epilogue ----------------
// XCD-aware A-reuse schedule (T1, bijective).
// flags: 1 = relu, 2 = accumulate into C, 4 = qkv scatter store (fp16 head-major)
__global__ __launch_bounds__(256)
void k_gemm16(const _Float16* __restrict__ A, const _Float16* __restrict__ Bt,
              const float* __restrict__ bias, float* __restrict__ C,
              _Float16* __restrict__ q16, _Float16* __restrict__ k16, _Float16* __restrict__ v16,
              int Mr, int K, int N, int flags)
{
  __shared__ __attribute__((aligned(16))) _Float16 As[128 * 32];
  __shared__ __attribute__((aligned(16))) _Float16 Bs[128 * 32];
  int NT = N >> 7;
  int nwg = gridDim.x;
  int q8 = nwg >> 3, r8 = nwg & 7;
  int xcd = blockIdx.x & 7, sidx = blockIdx.x >> 3;
  int wgid = (xcd < r8) ? (xcd * (q8 + 1) + sidx)
                        : (r8 * (q8 + 1) + (xcd - r8) * q8 + sidx);
  int bm = (wgid / NT) * 128, bn = (wgid % NT) * 128;
  int t = threadIdx.x;
  int lane = t & 63, w = t >> 6;
  int wm = (w >> 1) * 64, wn = (w & 1) * 64;
  int r = lane & 15, q = lane >> 4;
  int sub = lane >> 2;            // row within 16-row staging group
  int kq = (lane & 3) * 8;        // col (halves) within row

  const f4 zero = {0.f, 0.f, 0.f, 0.f};
  f4 acc[4][4];
  #pragma unroll
  for (int mi = 0; mi < 4; mi++)
    #pragma unroll
    for (int nj = 0; nj < 4; nj++) acc[mi][nj] = zero;

  for (int k0 = 0; k0 < K; k0 += 32) {
    #pragma unroll
    for (int c = 0; c < 2; c++) {
      int rowA = (w * 2 + c) * 16 + sub;
      int gmA = bm + rowA; if (gmA > Mr - 1) gmA = Mr - 1;
      gl_lds(A  + (size_t)gmA * K + k0 + kq,          As + (w * 2 + c) * 512);
      gl_lds(Bt + (size_t)(bn + rowA) * K + k0 + kq,  Bs + (w * 2 + c) * 512);
    }
    __syncthreads();
    h8 af[4], bf[4];
    #pragma unroll
    for (int i = 0; i < 4; i++) {
      af[i] = *(const h8*)(As + (wm + i * 16 + r) * 32 + q * 8);
      bf[i] = *(const h8*)(Bs + (wn + i * 16 + r) * 32 + q * 8);
    }
    #pragma unroll
    for (int mi = 0; mi < 4; mi++)
      #pragma unroll
      for (int nj = 0; nj < 4; nj++)
        acc[mi][nj] = __builtin_amdgcn_mfma_f32_16x16x32_f16(bf[nj], af[mi], acc[mi][nj], 0, 0, 0);
    __syncthreads();
  }
  #pragma unroll
  for (int mi = 0; mi < 4; mi++) {
    int gm = bm + wm + mi * 16 + r;
    if (gm >= Mr) continue;
    #pragma unroll
    for (int nj = 0; nj < 4; nj++) {
      int gn = bn + wn + nj * 16 + q * 4;
      f4 v = acc[mi][nj];
      if (flags & 4) {
        int which = gn >> 9, hh = (gn >> 6) & 7, dd = gn & 63;
        _Float16* dst = (which == 0) ? q16 : (which == 1) ? k16 : v16;
        h4 o = {(_Float16)v[0], (_Float16)v[1], (_Float16)v[2], (_Float16)v[3]};
        *(h4*)(dst + ((size_t)hh * NSEQP + gm) * 64 + dd) = o;
      } else {
        if (bias) { f4 bv = *(const f4*)(bias + gn); v += bv; }
        float* cp = C + (size_t)gm * N + gn;
        if (flags & 2) { f4 cv = *(const f4*)cp; v += cv; }
        if (flags & 1) {
          v[0] = fmaxf(v[0], 0.f); v[1] = fmaxf(v[1], 0.f);
          v[2] = fmaxf(v[2], 0.f); v[3] = fmaxf(v[3], 0.f);
        }
        *(f4*)cp = v;
      }
    }
  }
}

// ---------------- layernorm + front zero pad (fp16 out) ----------------
__global__ __launch_bounds__(256)
void k_ln_pad(const float* __restrict__ h, const float* __restrict__ w,
              const float* __restrict__ b, _Float16* __restrict__ xln)
{
  __shared__ float sbuf[8];
  int t = blockIdx.x;
  int tid = threadIdx.x;
  _Float16* out = xln + (size_t)t * DIMC;
  if (t < PADF) { out[tid] = (_Float16)0.f; out[tid + 256] = (_Float16)0.f; return; }
  const float* row = h + (size_t)(t - PADF) * DIMC;
  float x0 = row[tid], x1 = row[tid + 256];
  float mu = blkRed<4,false>(x0 + x1, sbuf) * (1.f / 512.f);
  float d0 = x0 - mu, d1 = x1 - mu;
  float var = blkRed<4,false>(d0 * d0 + d1 * d1, sbuf) * (1.f / 512.f);
  float rstd = rsqrtf(var + 1e-5f);
  out[tid]       = (_Float16)(d0 * rstd * w[tid]       + b[tid]);
  out[tid + 256] = (_Float16)(d1 * rstd * w[tid + 256] + b[tid + 256]);
}

// ---------------- v16 [h][t][64] -> vt16 [h][64][NSEQP] transpose ----------------
__global__ __launch_bounds__(256)
void k_vt(const _Float16* __restrict__ v16, _Float16* __restrict__ vt16)
{
  __shared__ _Float16 tl[64][72];
  int h = blockIdx.y;
  int t0 = blockIdx.x * 64;
  for (int c = threadIdx.x; c < 512; c += 256) {
    int row = c >> 3, ch = (c & 7) * 8;
    h8 v = {};
    if (t0 + row < NSEQP)
      v = *(const h8*)(v16 + ((size_t)h * NSEQP + t0 + row) * 64 + ch);
    *(h8*)&tl[row][ch] = v;
  }
  __syncthreads();
  int d = threadIdx.x & 63, tg = (threadIdx.x >> 6) * 16;
  if (t0 + tg < NSEQP) {
    _Float16 tmp[16];
    #pragma unroll
    for (int k = 0; k < 16; k++) tmp[k] = tl[tg + k][d];
    *(h8*)(vt16 + ((size_t)h * 64 + d) * NSEQP + t0 + tg)     = *(h8*)tmp;
    *(h8*)(vt16 + ((size_t)h * 64 + d) * NSEQP + t0 + tg + 8) = *(h8*)(tmp + 8);
  }
}

// ---------------- landmarks from fp16 q/k ----------------
__global__ __launch_bounds__(256)
void k_landmarks(const _Float16* __restrict__ q16, const _Float16* __restrict__ k16,
                 float* __restrict__ ql, float* __restrict__ kl,
                 _Float16* __restrict__ ql16, _Float16* __restrict__ kl16)
{
  __shared__ float red[2][16][64];
  int h = blockIdx.x >> 8, i = blockIdx.x & 255;
  int jg = threadIdx.x >> 4, d4 = (threadIdx.x & 15) * 4;
  const _Float16* qb = q16 + ((size_t)h * NSEQP + i * LWIN) * 64;
  const _Float16* kb = k16 + ((size_t)h * NSEQP + i * LWIN) * 64;
  float sq[4] = {}, sk[4] = {};
  for (int j = jg; j < LWIN; j += 16) {
    h4 qv = *(const h4*)(qb + j * 64 + d4);
    h4 kv = *(const h4*)(kb + j * 64 + d4);
    #pragma unroll
    for (int c = 0; c < 4; c++) { sq[c] += (float)qv[c]; sk[c] += (float)kv[c]; }
  }
  #pragma unroll
  for (int c = 0; c < 4; c++) { red[0][jg][d4 + c] = sq[c]; red[1][jg][d4 + c] = sk[c]; }
  __syncthreads();
  if (threadIdx.x < 64) {
    int d = threadIdx.x;
    float aq = 0.f, ak = 0.f;
    #pragma unroll
    for (int g = 0; g < 16; g++) { aq += red[0][g][d]; ak += red[1][g][d]; }
    aq *= (0.125f / (float)LWIN);
    ak *= (1.f / (float)LWIN);
    size_t o = ((size_t)h * MLM + i) * DH + d;
    ql[o] = aq; kl[o] = ak;
    ql16[o] = (_Float16)aq;
    kl16[o] = (_Float16)(ak * 0.125f);   // fold q-scale for attn1
  }
}

// ---------------- attn2 = softmax(q_l @ k_l^T) ----------------
__global__ __launch_bounds__(256)
void k_attn2(const float* __restrict__ ql, const float* __restrict__ kl, float* __restrict__ a2)
{
  __shared__ float qrow[DH];
  __shared__ float sbuf[8];
  int h = blockIdx.x >> 8, i = blockIdx.x & 255;
  int j = threadIdx.x;
  if (j < DH) qrow[j] = ql[(h * MLM + i) * DH + j];
  __syncthreads();
  const float* krow = kl + (size_t)(h * MLM + j) * DH;
  float s = 0.f;
  #pragma unroll 16
  for (int d = 0; d < DH; d++) s += qrow[d] * krow[d];
  float mx = blkRed<4,true>(s, sbuf);
  float e = __expf(s - mx);
  float sum = blkRed<4,false>(e, sbuf);
  a2[((size_t)h * MLM + i) * MLM + j] = e / sum;
}

// ---------------- pinv init: per-head row/col sum maxima ----------------
__global__ __launch_bounds__(256)
void k_pinv_init1(const float* __restrict__ a2, float* __restrict__ hmax)
{
  __shared__ float sbuf[8];
  int h = blockIdx.x;
  int j = threadIdx.x;
  const float* A = a2 + (size_t)h * MLM * MLM;
  float cs = 0.f, rs = 0.f;
  for (int i = 0; i < MLM; i++) cs += A[i * MLM + j];
  for (int k = 0; k < MLM; k++) rs += A[j * MLM + k];
  float rmax = blkRed<4,true>(rs, sbuf);
  float cmax = blkRed<4,true>(cs, sbuf);
  if (j == 0) { hmax[h * 2] = rmax; hmax[h * 2 + 1] = cmax; }
}

// ---------------- pinv prep: a2 fp32 -> pair arrays; z0 = scal*a2^T (pairs, both layouts) ----
// scal computed inline from hmax (init2 folded in: 16 scalar loads per thread).
__global__ __launch_bounds__(256)
void k_pinv_prep(const float* __restrict__ a2, const float* __restrict__ hmax,
                 _Float16* __restrict__ a2h, _Float16* __restrict__ a2l,
                 _Float16* __restrict__ zh,  _Float16* __restrict__ zl,
                 _Float16* __restrict__ zth, _Float16* __restrict__ ztl)
{
  __shared__ float tl[64][65];
  int h = blockIdx.x >> 4, tile = blockIdx.x & 15;
  int ti = (tile >> 2) * 64, tj = (tile & 3) * 64;
  float rm = 0.f, cm = 0.f;
  #pragma unroll
  for (int hh = 0; hh < HEADS; hh++) {
    rm = fmaxf(rm, hmax[2 * hh]);
    cm = fmaxf(cm, hmax[2 * hh + 1]);
  }
  float s = 1.f / (rm * cm);
  int row = threadIdx.x >> 4, c4 = (threadIdx.x & 15) * 4;
  #pragma unroll
  for (int rr = 0; rr < 4; rr++) {
    int rloc = rr * 16 + row;
    f4 v = *(const f4*)(a2 + ((size_t)h * MLM + ti + rloc) * MLM + tj + c4);
    h4 hi, lo, zhi, zlo;
    #pragma unroll
    for (int c = 0; c < 4; c++) {
      hi[c] = (_Float16)v[c];
      lo[c] = (_Float16)(v[c] - (float)hi[c]);
      float zv = v[c] * s;
      zhi[c] = (_Float16)zv;
      zlo[c] = (_Float16)(zv - (float)zhi[c]);
      tl[rloc][c4 + c] = zv;
    }
    size_t idx = ((size_t)h * MLM + ti + rloc) * MLM + tj + c4;
    *(h4*)(a2h + idx) = hi;  *(h4*)(a2l + idx) = lo;
    *(h4*)(zth + idx) = zhi; *(h4*)(ztl + idx) = zlo;
  }
  __syncthreads();
  // z[tj+r][ti+c] = tl[c][r]
  #pragma unroll
  for (int rr = 0; rr < 4; rr++) {
    int rloc = rr * 16 + row;
    h4 hi, lo;
    #pragma unroll
    for (int c = 0; c < 4; c++) {
      float zv = tl[c4 + c][rloc];
      hi[c] = (_Float16)zv;
      lo[c] = (_Float16)(zv - (float)hi[c]);
    }
    size_t idx = ((size_t)h * MLM + tj + rloc) * MLM + ti + c4;
    *(h4*)(zh + idx) = hi; *(h4*)(zl + idx) = lo;
  }
}

// ---------------- split-fp16 pair MFMA bmm (R6 staged version — gl_lds, coalesced) ----
__global__ __launch_bounds__(256)
void k_pbmm(const _Float16* __restrict__ Ah, const _Float16* __restrict__ Al,
            const _Float16* __restrict__ Bth, const _Float16* __restrict__ Btl,
            const _Float16* __restrict__ Eh, const _Float16* __restrict__ El,
            _Float16* __restrict__ Ch,  _Float16* __restrict__ Cl,
            _Float16* __restrict__ Cth, _Float16* __restrict__ Ctl,
            int N, float c0, float c1)
{
  __shared__ __attribute__((aligned(16))) _Float16 lds[16384];
  _Float16 *Ash = lds, *Asl = lds + 2048, *Bsh = lds + 4096, *Bsl = lds + 6144;
  _Float16 *Tt0 = lds + 8192, *Tt1 = lds + 12288;
  int tn = N >> 6;
  int bm = (blockIdx.x / tn) * 64, bn = (blockIdx.x % tn) * 64;
  int h = blockIdx.y;
  int tid = threadIdx.x, lane = tid & 63, w = tid >> 6;
  int wm = (w >> 1) * 32, wn = (w & 1) * 32;
  int r = lane & 15, q = lane >> 4;
  int sub = lane >> 2, kq = (lane & 3) * 8;

  const _Float16* Ahb = Ah + ((size_t)h * MLM + bm) * MLM;
  const _Float16* Alb = Al + ((size_t)h * MLM + bm) * MLM;
  const _Float16* Bhb = Bth + ((size_t)h * N + bn) * MLM;
  const _Float16* Blb = Btl + ((size_t)h * N + bn) * MLM;

  const f4 zero = {0.f, 0.f, 0.f, 0.f};
  f4 acc[2][2];
  #pragma unroll
  for (int mi = 0; mi < 2; mi++)
    #pragma unroll
    for (int nj = 0; nj < 2; nj++) acc[mi][nj] = zero;

  for (int k0 = 0; k0 < MLM; k0 += 32) {
    int rw = w * 16 + sub;
    gl_lds(Ahb + (size_t)rw * MLM + k0 + kq, Ash + w * 512);
    gl_lds(Alb + (size_t)rw * MLM + k0 + kq, Asl + w * 512);
    gl_lds(Bhb + (size_t)rw * MLM + k0 + kq, Bsh + w * 512);
    gl_lds(Blb + (size_t)rw * MLM + k0 + kq, Bsl + w * 512);
    __syncthreads();
    h8 afh[2], afl[2], bfh[2], bfl[2];
    #pragma unroll
    for (int i = 0; i < 2; i++) {
      afh[i] = *(const h8*)(Ash + (wm + i * 16 + r) * 32 + q * 8);
      afl[i] = *(const h8*)(Asl + (wm + i * 16 + r) * 32 + q * 8);
      bfh[i] = *(const h8*)(Bsh + (wn + i * 16 + r) * 32 + q * 8);
      bfl[i] = *(const h8*)(Bsl + (wn + i * 16 + r) * 32 + q * 8);
    }
    #pragma unroll
    for (int mi = 0; mi < 2; mi++)
      #pragma unroll
      for (int nj = 0; nj < 2; nj++) {
        acc[mi][nj] = __builtin_amdgcn_mfma_f32_16x16x32_f16(afh[mi], bfh[nj], acc[mi][nj], 0, 0, 0);
        acc[mi][nj] = __builtin_amdgcn_mfma_f32_16x16x32_f16(afh[mi], bfl[nj], acc[mi][nj], 0, 0, 0);
        acc[mi][nj] = __builtin_amdgcn_mfma_f32_16x16x32_f16(afl[mi], bfh[nj], acc[mi][nj], 0, 0, 0);
      }
    __syncthreads();
  }
  // epilogue: straight stores + swizzled LDS transpose
  #pragma unroll
  for (int mi = 0; mi < 2; mi++) {
    #pragma unroll
    for (int i = 0; i < 4; i++) {
      int lm = wm + mi * 16 + q * 4 + i;       // local row 0..63
      #pragma unroll
      for (int nj = 0; nj < 2; nj++) {
        int ln = wn + nj * 16 + r;             // local col 0..63
        size_t ide = ((size_t)h * MLM + bm + lm) * N + bn + ln;
        float v = c0 * acc[mi][nj][i];
        if (Eh) v += c1 * ((float)Eh[ide] + (float)El[ide]);
        _Float16 hi = (_Float16)v;
        _Float16 lo = (_Float16)(v - (float)hi);
        if (Ch) { Ch[ide] = hi; Cl[ide] = lo; }
        int sw = lm ^ ((ln & 7) << 3);         // XOR swizzle, keeps 8-half runs contiguous
        Tt0[ln * 64 + sw] = hi;
        Tt1[ln * 64 + sw] = lo;
      }
    }
  }
  __syncthreads();
  {
    int row = tid >> 2;
    int cb0 = (tid & 3) * 16;
    #pragma unroll
    for (int sg = 0; sg < 2; sg++) {
      int cb = cb0 + sg * 8;
      int swc = cb ^ ((row & 7) << 3);
      h8 vh = *(const h8*)(Tt0 + row * 64 + swc);
      h8 vl = *(const h8*)(Tt1 + row * 64 + swc);
      size_t idt = ((size_t)h * N + bn + row) * MLM + bm + cb;
      *(h8*)(Cth + idt) = vh;
      *(h8*)(Ctl + idt) = vl;
    }
  }
}

// ---------------- flash attn3: partials of softmax(ql @ k^T) @ v ----------------
// Defer-max online softmax (T13) + manual software pipeline: V-operand loads
// hoisted to iteration top; next tile's K loads issued right after this tile's
// QK MFMAs (regs dead there) so they fly under softmax+PV despite the fences.
__global__ __launch_bounds__(256)
void k_attn3(const _Float16* __restrict__ ql16, const _Float16* __restrict__ k16,
             const _Float16* __restrict__ vt16,
             float* __restrict__ pm, float* __restrict__ ps, float* __restrict__ pacc)
{
  __shared__ __attribute__((aligned(16))) _Float16 Pl[4][64 * 40];
  int c = blockIdx.x, h = blockIdx.y;
  int tid = threadIdx.x, lane = tid & 63, w = tid >> 6;
  int r = lane & 15, q = lane >> 4;
  int t0 = c * PER;
  int m0 = w * 64;
  const _Float16* qlh = ql16 + (size_t)h * MLM * 64;
  const _Float16* kh  = k16  + (size_t)h * NSEQP * 64;
  const _Float16* vh  = vt16 + (size_t)h * 64 * NSEQP;
  _Float16* Pw = &Pl[w][0];

  h8 af[4][2];
  #pragma unroll
  for (int mt = 0; mt < 4; mt++)
    #pragma unroll
    for (int ks = 0; ks < 2; ks++)
      af[mt][ks] = *(const h8*)(qlh + (size_t)(m0 + mt * 16 + r) * 64 + ks * 32 + q * 8);

  const f4 zero = {0.f, 0.f, 0.f, 0.f};
  f4 acc[4][4];
  float mrun[4][4], lrun[4][4];
  #pragma unroll
  for (int mt = 0; mt < 4; mt++) {
    #pragma unroll
    for (int nd = 0; nd < 4; nd++) acc[mt][nd] = zero;
    #pragma unroll
    for (int i = 0; i < 4; i++) { mrun[mt][i] = -1e30f; lrun[mt][i] = 0.f; }
  }

  // preload tile 0 K fragments
  h8 kb0[2], kb1[2];
  #pragma unroll
  for (int nt = 0; nt < 2; nt++) {
    kb0[nt] = *(const h8*)(kh + (size_t)(t0 + nt * 16 + r) * 64 + q * 8);
    kb1[nt] = *(const h8*)(kh + (size_t)(t0 + nt * 16 + r) * 64 + 32 + q * 8);
  }

  for (int tb = 0; tb < 20; tb++) {
    int tt = t0 + tb * 32;
    // issue this tile's V loads early (consumed in PV after softmax)
    h8 bv[4];
    #pragma unroll
    for (int nd = 0; nd < 4; nd++)
      bv[nd] = *(const h8*)(vh + (size_t)(nd * 16 + r) * NSEQP + tt + q * 8);
    f4 S[4][2];
    #pragma unroll
    for (int mt = 0; mt < 4; mt++) { S[mt][0] = zero; S[mt][1] = zero; }
    #pragma unroll
    for (int nt = 0; nt < 2; nt++) {
      #pragma unroll
      for (int mt = 0; mt < 4; mt++) {
        S[mt][nt] = __builtin_amdgcn_mfma_f32_16x16x32_f16(af[mt][0], kb0[nt], S[mt][nt], 0, 0, 0);
        S[mt][nt] = __builtin_amdgcn_mfma_f32_16x16x32_f16(af[mt][1], kb1[nt], S[mt][nt], 0, 0, 0);
      }
    }
    // issue next tile's K loads (kb regs dead after QK) -> fly under softmax+PV
    {
      int ttn = (tb < 19) ? tt + 32 : t0;
      #pragma unroll
      for (int nt = 0; nt < 2; nt++) {
        kb0[nt] = *(const h8*)(kh + (size_t)(ttn + nt * 16 + r) * 64 + q * 8);
        kb1[nt] = *(const h8*)(kh + (size_t)(ttn + nt * 16 + r) * 64 + 32 + q * 8);
      }
    }
    if (tb == 19) {
      #pragma unroll
      for (int nt = 0; nt < 2; nt++) {
        bool valid = (tb * 32 + nt * 16 + r) < PER;
        #pragma unroll
        for (int mt = 0; mt < 4; mt++)
          #pragma unroll
          for (int i = 0; i < 4; i++)
            S[mt][nt][i] = valid ? S[mt][nt][i] : -1e30f;
      }
    }
    #pragma unroll
    for (int mt = 0; mt < 4; mt++) {
      bool tg = false;
      #pragma unroll
      for (int i = 0; i < 4; i++)
        tg = tg || (S[mt][0][i] > mrun[mt][i] + 8.f) || (S[mt][1][i] > mrun[mt][i] + 8.f);
      if (__any(tg)) {
        float nm[4], al[4];
        #pragma unroll
        for (int i = 0; i < 4; i++) {
          nm[i] = fmaxf(S[mt][0][i], S[mt][1][i]);
          #pragma unroll
          for (int o = 1; o < 16; o <<= 1) nm[i] = fmaxf(nm[i], __shfl_xor(nm[i], o, 64));
          nm[i] = fmaxf(nm[i], mrun[mt][i]);
          al[i] = __expf(mrun[mt][i] - nm[i]);
          mrun[mt][i] = nm[i];
          lrun[mt][i] *= al[i];
        }
        #pragma unroll
        for (int nd = 0; nd < 4; nd++)
          #pragma unroll
          for (int i = 0; i < 4; i++) acc[mt][nd][i] *= al[i];
      }
      #pragma unroll
      for (int i = 0; i < 4; i++) {
        float p0 = __expf(S[mt][0][i] - mrun[mt][i]);
        float p1 = __expf(S[mt][1][i] - mrun[mt][i]);
        lrun[mt][i] += p0 + p1;
        S[mt][0][i] = p0; S[mt][1][i] = p1;
      }
      #pragma unroll
      for (int nt = 0; nt < 2; nt++)
        #pragma unroll
        for (int i = 0; i < 4; i++)
          Pw[(mt * 16 + q * 4 + i) * 40 + nt * 16 + r] = (_Float16)S[mt][nt][i];
    }
    WAVE_LDS_FENCE();
    #pragma unroll
    for (int mt = 0; mt < 4; mt++) {
      h8 ap = *(const h8*)(Pw + (mt * 16 + r) * 40 + q * 8);
      #pragma unroll
      for (int nd = 0; nd < 4; nd++)
        acc[mt][nd] = __builtin_amdgcn_mfma_f32_16x16x32_f16(ap, bv[nd], acc[mt][nd], 0, 0, 0);
    }
    WAVE_LDS_FENCE();
  }
  // finalize the deferred row-sum (one butterfly over the 16 r-lanes)
  #pragma unroll
  for (int mt = 0; mt < 4; mt++)
    #pragma unroll
    for (int i = 0; i < 4; i++)
      #pragma unroll
      for (int o = 1; o < 16; o <<= 1) lrun[mt][i] += __shfl_xor(lrun[mt][i], o, 64);
  int cidx = h * CHUNKS + c;
  #pragma unroll
  for (int mt = 0; mt < 4; mt++) {
    int rowb = m0 + mt * 16 + q * 4;
    if (r == 0) {
      #pragma unroll
      for (int i = 0; i < 4; i++) {
        pm[(size_t)cidx * MLM + rowb + i] = mrun[mt][i];
        ps[(size_t)cidx * MLM + rowb + i] = lrun[mt][i];
      }
    }
    #pragma unroll
    for (int nd = 0; nd < 4; nd++)
      #pragma unroll
      for (int i = 0; i < 4; i++)
        pacc[((size_t)cidx * MLM + rowb + i) * 64 + nd * 16 + r] = acc[mt][nd][i];
  }
}

// reduce partials -> avT pairs [h][64][256]
__global__ __launch_bounds__(64)
void k_attn3_reduce(const float* __restrict__ pm, const float* __restrict__ ps,
                    const float* __restrict__ pacc,
                    _Float16* __restrict__ avth, _Float16* __restrict__ avtl)
{
  int h = blockIdx.x >> 8, i = blockIdx.x & 255;
  int d = threadIdx.x;
  float m = -1e30f;
  for (int c = 0; c < CHUNKS; c++) m = fmaxf(m, pm[(h * CHUNKS + c) * MLM + i]);
  float l = 0.f, a = 0.f;
  for (int c = 0; c < CHUNKS; c++) {
    int idx = (h * CHUNKS + c) * MLM + i;
    float w = __expf(pm[idx] - m);
    l += ps[idx] * w;
    a += pacc[(size_t)idx * DH + d] * w;
  }
  float v = a / l;
  _Float16 hi = (_Float16)v;
  size_t o = ((size_t)h * DH + d) * MLM + i;
  avth[o] = hi;
  avtl[o] = (_Float16)(v - (float)hi);
}

// ---------------- depthwise 33-tap conv on v -> xat16 ----------------
__global__ __launch_bounds__(256)
void k_conv(const _Float16* __restrict__ v16, const float* __restrict__ rw,
            _Float16* __restrict__ xat)
{
  __shared__ float tl[160][64];
  int h = blockIdx.y;
  int t0 = PADF + blockIdx.x * 128;
  for (int c = threadIdx.x; c < 160 * 16; c += 256) {
    int row = c >> 4, d4 = (c & 15) * 4;
    int ts = t0 - 16 + row;
    f4 val = {0.f, 0.f, 0.f, 0.f};
    if (ts >= 0 && ts < NSEQ) {
      h4 hv = *(const h4*)(v16 + ((size_t)h * NSEQP + ts) * 64 + d4);
      val[0] = (float)hv[0]; val[1] = (float)hv[1]; val[2] = (float)hv[2]; val[3] = (float)hv[3];
    }
    *(f4*)&tl[row][d4] = val;
  }
  __syncthreads();
  float wt[33];
  #pragma unroll
  for (int tap = 0; tap < 33; tap++) wt[tap] = rw[h * 33 + tap];
  int d4 = (threadIdx.x & 15) * 4, r0 = threadIdx.x >> 4;
  #pragma unroll
  for (int k = 0; k < 8; k++) {
    int r = k * 16 + r0;
    int t = t0 + r;
    f4 acc = {0.f, 0.f, 0.f, 0.f};
    #pragma unroll
    for (int tap = 0; tap < 33; tap++) {
      f4 vv = *(const f4*)&tl[r + tap][d4];
      acc[0] += wt[tap] * vv[0]; acc[1] += wt[tap] * vv[1];
      acc[2] += wt[tap] * vv[2]; acc[3] += wt[tap] * vv[3];
    }
    if (t < NSEQ) {
      h4 o = {(_Float16)acc[0], (_Float16)acc[1], (_Float16)acc[2], (_Float16)acc[3]};
      *(h4*)(xat + (size_t)t * DIMC + h * 64 + d4) = o;
    }
  }
}

// ---------------- flash attn1: xat += softmax(q @ kl^T) @ w2, attn3-style ----------------
// Block = 256 q-rows x 1 head (4 waves x 64 rows). Defer-max online softmax (T13)
// + manual software pipeline (bw hoisted; next-tile kl loads issued post-QK).
__global__ __launch_bounds__(256)
void k_attn1(const _Float16* __restrict__ q16, const _Float16* __restrict__ kl16,
             const _Float16* __restrict__ w2t16, _Float16* __restrict__ xat)
{
  __shared__ __attribute__((aligned(16))) _Float16 Pl[4][64 * 40];   // P tile; reused as output staging
  int h = blockIdx.y;
  int t0 = blockIdx.x * 256;            // 157 * 256 = NSEQ exactly
  int tid = threadIdx.x, lane = tid & 63, w = tid >> 6;
  int r = lane & 15, q = lane >> 4;
  int m0 = w * 64;
  const _Float16* qh  = q16  + (size_t)h * NSEQP * 64;
  const _Float16* klh = kl16 + (size_t)h * MLM * 64;
  const _Float16* w2h = w2t16 + (size_t)h * 64 * 256;
  _Float16* Pw = &Pl[w][0];

  h8 af[4][2];
  #pragma unroll
  for (int mt = 0; mt < 4; mt++)
    #pragma unroll
    for (int ks = 0; ks < 2; ks++)
      af[mt][ks] = *(const h8*)(qh + (size_t)(t0 + m0 + mt * 16 + r) * 64 + ks * 32 + q * 8);

  const f4 zero = {0.f, 0.f, 0.f, 0.f};
  f4 acc[4][4];
  float mrun[4][4], lrun[4][4];
  #pragma unroll
  for (int mt = 0; mt < 4; mt++) {
    #pragma unroll
    for (int nd = 0; nd < 4; nd++) acc[mt][nd] = zero;
    #pragma unroll
    for (int i = 0; i < 4; i++) { mrun[mt][i] = -1e30f; lrun[mt][i] = 0.f; }
  }

  // preload tile 0 K fragments
  h8 kb0[2], kb1[2];
  #pragma unroll
  for (int nt = 0; nt < 2; nt++) {
    kb0[nt] = *(const h8*)(klh + (size_t)(nt * 16 + r) * 64 + q * 8);
    kb1[nt] = *(const h8*)(klh + (size_t)(nt * 16 + r) * 64 + 32 + q * 8);
  }

  for (int tb = 0; tb < 8; tb++) {      // 8 tiles x 32 landmarks = 256
    int tt = tb * 32;
    // issue this tile's w2 loads early (consumed in PV after softmax)
    h8 bw[4];
    #pragma unroll
    for (int nd = 0; nd < 4; nd++)
      bw[nd] = *(const h8*)(w2h + (size_t)(nd * 16 + r) * 256 + tt + q * 8);
    f4 S[4][2];
    #pragma unroll
    for (int mt = 0; mt < 4; mt++) { S[mt][0] = zero; S[mt][1] = zero; }
    #pragma unroll
    for (int nt = 0; nt < 2; nt++) {
      #pragma unroll
      for (int mt = 0; mt < 4; mt++) {
        S[mt][nt] = __builtin_amdgcn_mfma_f32_16x16x32_f16(af[mt][0], kb0[nt], S[mt][nt], 0, 0, 0);
        S[mt][nt] = __builtin_amdgcn_mfma_f32_16x16x32_f16(af[mt][1], kb1[nt], S[mt][nt], 0, 0, 0);
      }
    }
    // issue next tile's kl loads (kb regs dead after QK)
    {
      int ttn = (tb < 7) ? tt + 32 : 0;
      #pragma unroll
      for (int nt = 0; nt < 2; nt++) {
        kb0[nt] = *(const h8*)(klh + (size_t)(ttn + nt * 16 + r) * 64 + q * 8);
        kb1[nt] = *(const h8*)(klh + (size_t)(ttn + nt * 16 + r) * 64 + 32 + q * 8);
      }
    }
    #pragma unroll
    for (int mt = 0; mt < 4; mt++) {
      bool tg = false;
      #pragma unroll
      for (int i = 0; i < 4; i++)
        tg = tg || (S[mt][0][i] > mrun[mt][i] + 8.f) || (S[mt][1][i] > mrun[mt][i] + 8.f);
      if (__any(tg)) {
        float nm[4], al[4];
        #pragma unroll
        for (int i = 0; i < 4; i++) {
          nm[i] = fmaxf(S[mt][0][i], S[mt][1][i]);
          #pragma unroll
          for (int o = 1; o < 16; o <<= 1) nm[i] = fmaxf(nm[i], __shfl_xor(nm[i], o, 64));
          nm[i] = fmaxf(nm[i], mrun[mt][i]);
          al[i] = __expf(mrun[mt][i] - nm[i]);
          mrun[mt][i] = nm[i];
          lrun[mt][i] *= al[i];
        }
        #pragma unroll
        for (int nd = 0; nd < 4; nd++)
          #pragma unroll
          for (int i = 0; i < 4; i++) acc[mt][nd][i] *= al[i];
      }
      #pragma unroll
      for (int i = 0; i < 4; i++) {
        float p0 = __expf(S[mt][0][i] - mrun[mt][i]);
        float p1 = __expf(S[mt][1][i] - mrun[mt][i]);
        lrun[mt][i] += p0 + p1;
        S[mt][0][i] = p0; S[mt][1][i] = p1;
      }
      #pragma unroll
      for (int nt = 0; nt < 2; nt++)
        #pragma unroll
        for (int i = 0; i < 4; i++)
          Pw[(mt * 16 + q * 4 + i) * 40 + nt * 16 + r] = (_Float16)S[mt][nt][i];
    }
    WAVE_LDS_FENCE();
    #pragma unroll
    for (int mt = 0; mt < 4; mt++) {
      h8 ap = *(const h8*)(Pw + (mt * 16 + r) * 40 + q * 8);
      #pragma unroll
      for (int nd = 0; nd < 4; nd++)
        acc[mt][nd] = __builtin_amdgcn_mfma_f32_16x16x32_f16(ap, bw[nd], acc[mt][nd], 0, 0, 0);
    }
    WAVE_LDS_FENCE();
  }
  // finalize the deferred row-sum
  #pragma unroll
  for (int mt = 0; mt < 4; mt++)
    #pragma unroll
    for (int i = 0; i < 4; i++)
      #pragma unroll
      for (int o = 1; o < 16; o <<= 1) lrun[mt][i] += __shfl_xor(lrun[mt][i], o, 64);
  // normalize + add into xat, via per-wave LDS transpose (two 32-row halves)
  #pragma unroll
  for (int half = 0; half < 2; half++) {
    #pragma unroll
    for (int mt2 = 0; mt2 < 2; mt2++) {
      int mt = half * 2 + mt2;
      float li[4];
      #pragma unroll
      for (int i = 0; i < 4; i++) li[i] = 1.f / lrun[mt][i];
      #pragma unroll
      for (int nd = 0; nd < 4; nd++)
        #pragma unroll
        for (int i = 0; i < 4; i++)
          Pw[(mt2 * 16 + q * 4 + i) * 72 + nd * 16 + r] = (_Float16)(acc[mt][nd][i] * li[i]);
    }
    WAVE_LDS_FENCE();
    #pragma unroll
    for (int c = 0; c < 4; c++) {
      int row = c * 8 + (lane >> 3);    // 0..31
      int ch = (lane & 7) * 8;
      int t = t0 + m0 + half * 32 + row;
      if (t >= PADF) {
        _Float16* dst = xat + (size_t)t * DIMC + h * 64 + ch;
        h8 cv = *(h8*)dst;
        h8 pv = *(const h8*)(Pw + row * 72 + ch);
        h8 o;
        #pragma unroll
        for (int k = 0; k < 8; k++) o[k] = (_Float16)((float)cv[k] + (float)pv[k]);
        *(h8*)dst = o;
      }
    }
    WAVE_LDS_FENCE();                   // WAR before next half reuses Pw
  }
}

// ---------------- PPEG ----------------
__global__ __launch_bounds__(256)
void k_transpose_fw(const float* __restrict__ h, float* __restrict__ g)
{
  __shared__ float tile[32][33];
  int pb = blockIdx.x * 32, cb = blockIdx.y * 32;
  int x = threadIdx.x & 31, y0 = threadIdx.x >> 5;
  #pragma unroll
  for (int yy = y0; yy < 32; yy += 8)
    tile[yy][x] = h[(size_t)(1 + pb + yy) * DIMC + cb + x];
  __syncthreads();
  #pragma unroll
  for (int yy = y0; yy < 32; yy += 8)
    g[(size_t)(cb + yy) * NPATCH + pb + x] = tile[x][yy];
}

// 32x32 output tile, 2 channels/block packed as float2 (-> v_pk_fma_f32).
__global__ __launch_bounds__(256)
void k_ppeg(const float* __restrict__ g,
            const float* __restrict__ w7, const float* __restrict__ b7,
            const float* __restrict__ w5, const float* __restrict__ b5,
            const float* __restrict__ w3, const float* __restrict__ b3,
            float* __restrict__ o)
{
  __shared__ f2 tl[38][40];             // 12.2 KB
  int cp = blockIdx.y;
  int c0 = cp * 2, c1 = c0 + 1;
  int ty0 = (blockIdx.x / 7) * 32, tx0 = (blockIdx.x % 7) * 32;
  const float* g0 = g + (size_t)c0 * NPATCH;
  const float* g1 = g + (size_t)c1 * NPATCH;
  for (int e = threadIdx.x; e < 38 * 40; e += 256) {
    int row = e / 40, col = e % 40;
    int y = ty0 - 3 + row, x = tx0 - 3 + col;
    f2 v = {0.f, 0.f};
    if (y >= 0 && y < GRID && x >= 0 && x < GRID && col < 38) {
      v[0] = g0[y * GRID + x];
      v[1] = g1[y * GRID + x];
    }
    tl[row][col] = v;
  }
  __syncthreads();
  int tx4 = (threadIdx.x & 7) * 4, ty = threadIdx.x >> 3;   // 32 rows x 8 col-groups
  f2 bb = {b7[c0] + b5[c0] + b3[c0], b7[c1] + b5[c1] + b3[c1]};
  f2 acc[4];
  #pragma unroll
  for (int j = 0; j < 4; j++) acc[j] = bb + tl[ty + 3][tx4 + 3 + j];
  #pragma unroll
  for (int ky = 0; ky < 7; ky++) {
    f2 f[10];
    #pragma unroll
    for (int k = 0; k < 5; k++)
      *(f4*)&f[k * 2] = *(const f4*)&tl[ty + ky][tx4 + k * 2];
    #pragma unroll
    for (int kx = 0; kx < 7; kx++) {
      f2 wv = {w7[c0 * 49 + ky * 7 + kx], w7[c1 * 49 + ky * 7 + kx]};
      #pragma unroll
      for (int j = 0; j < 4; j++) acc[j] += wv * f[kx + j];
    }
    if (ky >= 1 && ky <= 5) {
      #pragma unroll
      for (int kx = 0; kx < 5; kx++) {
        f2 wv = {w5[c0 * 25 + (ky - 1) * 5 + kx], w5[c1 * 25 + (ky - 1) * 5 + kx]};
        #pragma unroll
        for (int j = 0; j < 4; j++) acc[j] += wv * f[1 + kx + j];
      }
    }
    if (ky >= 2 && ky <= 4) {
      #pragma unroll
      for (int kx = 0; kx < 3; kx++) {
        f2 wv = {w3[c0 * 9 + (ky - 2) * 3 + kx], w3[c1 * 9 + (ky - 2) * 3 + kx]};
        #pragma unroll
        for (int j = 0; j < 4; j++) acc[j] += wv * f[2 + kx + j];
      }
    }
  }
  int y = ty0 + ty, xb = tx0 + tx4;
  if (y < GRID && xb < GRID) {
    f4 o0 = {acc[0][0], acc[1][0], acc[2][0], acc[3][0]};
    f4 o1 = {acc[0][1], acc[1][1], acc[2][1], acc[3][1]};
    *(f4*)(o + (size_t)c0 * NPATCH + y * GRID + xb) = o0;
    *(f4*)(o + (size_t)c1 * NPATCH + y * GRID + xb) = o1;
  }
}

__global__ __launch_bounds__(256)
void k_transpose_bw(const float* __restrict__ g, float* __restrict__ h)
{
  __shared__ float tile[32][33];
  int pb = blockIdx.x * 32, cb = blockIdx.y * 32;
  int x = threadIdx.x & 31, y0 = threadIdx.x >> 5;
  #pragma unroll
  for (int yy = y0; yy < 32; yy += 8)
    tile[yy][x] = g[(size_t)(cb + yy) * NPATCH + pb + x];
  __syncthreads();
  #pragma unroll
  for (int yy = y0; yy < 32; yy += 8)
    h[(size_t)(1 + pb + yy) * DIMC + cb + x] = tile[x][yy];
}

// ---------------- final: layernorm(row 0) @ fc2 ----------------
__global__ __launch_bounds__(512)
void k_final(const float* __restrict__ h, const float* __restrict__ nw, const float* __restrict__ nb,
             const float* __restrict__ fw, const float* __restrict__ fb, float* __restrict__ out)
{
  __shared__ float sbuf[8];
  int d = threadIdx.x;
  float x = h[d];
  float mu = blkRed<8,false>(x, sbuf) * (1.f / 512.f);
  float dd = x - mu;
  float var = blkRed<8,false>(dd * dd, sbuf) * (1.f / 512.f);
  float cls = dd * rsqrtf(var + 1e-5f) * nw[d] + nb[d];
  float l0 = blkRed<8,false>(cls * fw[d * 2 + 0], sbuf);
  float l1 = blkRed<8,false>(cls * fw[d * 2 + 1], sbuf);
  if (d == 0) { out[0] = l0 + fb[0]; out[1] = l1 + fb[1]; }
}

// ---------------- host orchestration ----------------
struct Pair4 { _Float16 *h, *l, *th, *tl; };
struct WsPtrs {
  float *h, *ql, *kl, *a2, *hmax, *scal, *pm, *ps, *pacc;
  _Float16 *xat16, *q16, *k16, *v16, *vt16, *ql16, *kl16, *x16;
  _Float16 *a2h, *a2l, *avth, *avtl;
  Pair4 zA, zB, xz, u, u2, w2;
};

static void attention_layer(const WsPtrs& P,
                            const float* nw, const float* nb, const _Float16* qkvw16,
                            const _Float16* ow16, const float* ob, const float* rw,
                            hipStream_t stream)
{
  k_zpad<<<64, 256, 0, stream>>>(P.q16, P.k16, P.v16);
  k_ln_pad<<<NSEQ, 256, 0, stream>>>(P.h, nw, nb, P.xat16);
  k_gemm16<<<dim3((NSEQ / 128) * (1536 / 128)), 256, 0, stream>>>(
      P.xat16, qkvw16, nullptr, nullptr, P.q16, P.k16, P.v16, NSEQ, DIMC, 3 * DIMC, 4);
  k_vt<<<dim3(629, HEADS), 256, 0, stream>>>(P.v16, P.vt16);
  k_landmarks<<<HEADS * MLM, 256, 0, stream>>>(P.q16, P.k16, P.ql, P.kl, P.ql16, P.kl16);
  k_attn2<<<HEADS * MLM, 256, 0, stream>>>(P.ql, P.kl, P.a2);
  k_pinv_init1<<<HEADS, 256, 0, stream>>>(P.a2, P.hmax);
  k_pinv_prep<<<HEADS * 16, 256, 0, stream>>>(P.a2, P.hmax,
      P.a2h, P.a2l, P.zA.h, P.zA.l, P.zA.th, P.zA.tl);
  Pair4 z = P.zA, zn = P.zB;
  for (int it = 0; it < 6; it++) {
    k_pbmm<<<dim3(16, HEADS), 256, 0, stream>>>(P.a2h, P.a2l, z.th, z.tl,
        nullptr, nullptr, P.xz.h, P.xz.l, P.xz.th, P.xz.tl, MLM, 1.f, 0.f);
    // u and u2 are consumed ONLY in transposed layout -> skip straight stores
    k_pbmm<<<dim3(16, HEADS), 256, 0, stream>>>(P.xz.h, P.xz.l, P.xz.th, P.xz.tl,
        P.xz.h, P.xz.l, nullptr, nullptr, P.u.th, P.u.tl, MLM, -1.f, 7.f);
    k_pbmm<<<dim3(16, HEADS), 256, 0, stream>>>(P.xz.h, P.xz.l, P.u.th, P.u.tl,
        P.xz.h, P.xz.l, nullptr, nullptr, P.u2.th, P.u2.tl, MLM, -1.f, 15.f);
    k_pbmm<<<dim3(16, HEADS), 256, 0, stream>>>(z.h, z.l, P.u2.th, P.u2.tl,
        z.h, z.l, zn.h, zn.l, zn.th, zn.tl, MLM, -0.25f, 3.25f);
    Pair4 t = z; z = zn; zn = t;
  }
  k_attn3<<<dim3(CHUNKS, HEADS), 256, 0, stream>>>(P.ql16, P.k16, P.vt16, P.pm, P.ps, P.pacc);
  k_attn3_reduce<<<HEADS * MLM, 64, 0, stream>>>(P.pm, P.ps, P.pacc, P.avth, P.avtl);
  // w2 = z @ av ; only w2^T (hi/lo) is consumed by attn1 -> skip straight stores
  k_pbmm<<<dim3(4, HEADS), 256, 0, stream>>>(z.h, z.l, P.avth, P.avtl,
      nullptr, nullptr, nullptr, nullptr, P.w2.th, P.w2.tl, DH, 1.f, 0.f);
  k_conv<<<dim3(313, HEADS), 256, 0, stream>>>(P.v16, rw, P.xat16);
  k_attn1<<<dim3(157, HEADS), 256, 0, stream>>>(P.q16, P.kl16, P.w2.th, P.xat16);
  k_gemm16<<<dim3(((NTOK + 127) / 128) * (DIMC / 128)), 256, 0, stream>>>(
      P.xat16 + (size_t)PADF * DIMC, ow16, ob, P.h, nullptr, nullptr, nullptr, NTOK, DIMC, DIMC, 2);
}

extern "C" void kernel_launch(void* const* d_in, const int* in_sizes, int n_in,
                              void* d_out, int out_size, void* d_ws, size_t ws_size,
                              hipStream_t stream)
{
  const float* x      = (const float*)d_in[0];
  const float* fc1_w  = (const float*)d_in[1];
  const float* fc1_b  = (const float*)d_in[2];
  const float* cls    = (const float*)d_in[3];
  const float* l1_nw  = (const float*)d_in[4];
  const float* l1_nb  = (const float*)d_in[5];
  const float* l1_qkv = (const float*)d_in[6];
  const float* l1_ow  = (const float*)d_in[7];
  const float* l1_ob  = (const float*)d_in[8];
  const float* l1_rw  = (const float*)d_in[9];
  const float* p7w    = (const float*)d_in[10];
  const float* p7b    = (const float*)d_in[11];
  const float* p5w    = (const float*)d_in[12];
  const float* p5b    = (const float*)d_in[13];
  const float* p3w    = (const float*)d_in[14];
  const float* p3b    = (const float*)d_in[15];
  const float* l2_nw  = (const float*)d_in[16];
  const float* l2_nb  = (const float*)d_in[17];
  const float* l2_qkv = (const float*)d_in[18];
  const float* l2_ow  = (const float*)d_in[19];
  const float* l2_ob  = (const float*)d_in[20];
  const float* l2_rw  = (const float*)d_in[21];
  const float* nw     = (const float*)d_in[22];
  const float* nb     = (const float*)d_in[23];
  const float* fc2w   = (const float*)d_in[24];
  const float* fc2b   = (const float*)d_in[25];
  float* out = (float*)d_out;

  // ---- workspace carve-up (float offsets) ----
  float* W = (float*)d_ws;
  WsPtrs P;
  size_t off = 0;
  P.h     = W + off;               off += 20480512ull;   // 40001 x 512 fp32
  P.xat16 = (_Float16*)(W + off);  off += 10289152ull;   // NSEQ x 512 fp16
  float* R0 = W + off;                                   // fp16 q/k/v/vt region
  P.q16   = (_Float16*)R0;
  P.k16   = P.q16 + 20594688ull;   // 8 x 40224 x 64
  P.v16   = P.k16 + 20594688ull;
  P.vt16  = P.v16 + 20594688ull;   // 8 x 64 x 40224
  P.x16   = P.q16;                 // alias: fc1 input fp16 (dead before qkv GEMM)
  off += 41189376ull;              // 4 x 20594688 halfs / 2
  P.ql    = W + off; off += 131072;
  P.kl    = W + off; off += 131072;
  P.ql16  = (_Float16*)(W + off); off += 65536;
  P.kl16  = (_Float16*)(W + off); off += 65536;
  P.a2    = W + off; off += 524288;
  // fp16 pair region for pinv (sizes in halves -> float offsets are /2)
  _Float16* HP = (_Float16*)(W + off);
  size_t ho = 0;
  P.a2h = HP + ho; ho += 524288; P.a2l = HP + ho; ho += 524288;
  auto alloc4 = [&](Pair4& p, size_t n) {
    p.h = HP + ho; ho += n; p.l = HP + ho; ho += n;
    p.th = HP + ho; ho += n; p.tl = HP + ho; ho += n;
  };
  alloc4(P.zA, 524288); alloc4(P.zB, 524288); alloc4(P.xz, 524288);
  alloc4(P.u, 524288);  alloc4(P.u2, 524288);
  alloc4(P.w2, 131072);
  P.avth = HP + ho; ho += 131072; P.avtl = HP + ho; ho += 131072;
  off += (ho + 1) / 2;
  P.hmax  = W + off; P.scal = P.hmax + 16; off += 32;
  P.pm    = W + off; off += 131072;
  P.ps    = W + off; off += 131072;
  P.pacc  = W + off; off += 8388608;
  _Float16* fc1t  = (_Float16*)(W + off);   // 512x1024
  _Float16* qkv1t = fc1t  + 524288;         // 1536x512
  _Float16* out1t = qkv1t + 786432;         // 512x512
  _Float16* qkv2t = out1t + 262144;
  _Float16* out2t = qkv2t + 786432;

  // ---- weight fp32 -> fp16 transposed (N x K) ----
  k_wt16<<<dim3(INDIM / 32, DIMC / 32), 256, 0, stream>>>(fc1_w, fc1t, INDIM, DIMC);
  k_wt16<<<dim3(DIMC / 32, 1536 / 32), 256, 0, stream>>>(l1_qkv, qkv1t, DIMC, 1536);
  k_wt16<<<dim3(DIMC / 32, DIMC / 32), 256, 0, stream>>>(l1_ow, out1t, DIMC, DIMC);
  k_wt16<<<dim3(DIMC / 32, 1536 / 32), 256, 0, stream>>>(l2_qkv, qkv2t, DIMC, 1536);
  k_wt16<<<dim3(DIMC / 32, DIMC / 32), 256, 0, stream>>>(l2_ow, out2t, DIMC, DIMC);

  // fc1 + relu -> h rows 1..40000 ; cls token -> h row 0
  k_f32_to_f16<<<NPATCH * INDIM / 1024, 256, 0, stream>>>(x, P.x16);
  k_gemm16<<<dim3(((NPATCH + 127) / 128) * (DIMC / 128)), 256, 0, stream>>>(
      P.x16, fc1t, fc1_b, P.h + DIMC, nullptr, nullptr, nullptr, NPATCH, INDIM, DIMC, 1);
  k_set_cls<<<1, 512, 0, stream>>>(cls, P.h);

  // layer 1 attention
  attention_layer(P, l1_nw, l1_nb, qkv1t, out1t, l1_ob, l1_rw, stream);

  // PPEG (aliases the q/k/v fp16 region as fp32 scratch)
  float* fgrid = R0;
  float* cout  = R0 + 20480000ull;
  k_transpose_fw<<<dim3(NPATCH / 32, DIMC / 32), 256, 0, stream>>>(P.h, fgrid);
  k_ppeg<<<dim3(7 * 7, DIMC / 2), 256, 0, stream>>>(fgrid, p7w, p7b, p5w, p5b, p3w, p3b, cout);
  k_transpose_bw<<<dim3(NPATCH / 32, DIMC / 32), 256, 0, stream>>>(cout, P.h);

  // layer 2 attention
  attention_layer(P, l2_nw, l2_nb, qkv2t, out2t, l2_ob, l2_rw, stream);

  // final layernorm (cls row only) + fc2
  k_final<<<1, 512, 0, stream>>>(P.h, nw, nb, fc2w, fc2b, out);
}